// Round 12
// baseline (756.623 us; speedup 1.0000x reference)
//
#include <hip/hip_runtime.h>
#include <stdint.h>
#include <stddef.h>
#include <vector>
#include <algorithm>
#include <utility>

// Problem constants (B=2, L=4096, D=256, H=8, K=sqrt(L)=64, 10 Lloyd iters)
#define NPTS 8192
#define DIM  256
#define KC   64
#define LSEQ 4096
#define NB   2
#define KM_ITERS 10
#define NCHUNK 64     // 8192/128 points per summation chunk (bit-exact structure)
#define NBLK 64       // persistent kmeans blocks (block = chunk = cluster)
#define XPITCH 260    // padded LDS row for X tile (1040 B, 16B-aligned rows)
#define PPITCH 257    // padded LDS row for chunk-partials

// JAX threefry mode: 1 = partitionable (default since jax 0.4.36), 0 = original
#define JAX_THREEFRY_PARTITIONABLE 1

// ---------------- static device scratch (fully rewritten every call) --------
__device__ float g_R[NPTS * DIM];          // 8 MB   rotated points (read-only in kmeans, cached)
__device__ float g_xsq[NPTS];              // 32 KB  per-point squared norm (read-only, cached)
__device__ float g_centT[DIM * KC];        // 64 KB  centroids transposed [d][k] (SC1 relaxed)
__device__ float g_csq[KC];                // per-centroid squared norm (SC1 relaxed)
__device__ int   g_idx[NPTS];              // assignments, published every iter (SC1 relaxed)

// Flag-tree grid barrier state (monotone across graph replays; each block
// reads its own flag at entry as base — deterministic per replay).
__device__ unsigned g_arrive[NBLK * 16];   // block c uses g_arrive[c*16]
__device__ unsigned g_release2;            // release word (monotone)

// ---- relaxed agent-scope (SC1, coherence-point) access ----------------------
// Correctness of this model (SC1 data + vmcnt-drain + relaxed flags, no
// fences) was empirically validated in rounds 6 and 9 (absmax 0.0 both).
__device__ __forceinline__ float coh_ld(const float* p) {
  return __hip_atomic_load(p, __ATOMIC_RELAXED, __HIP_MEMORY_SCOPE_AGENT);
}
__device__ __forceinline__ int coh_ldi(const int* p) {
  return __hip_atomic_load(p, __ATOMIC_RELAXED, __HIP_MEMORY_SCOPE_AGENT);
}
__device__ __forceinline__ void coh_st(float* p, float v) {
  __hip_atomic_store(p, v, __ATOMIC_RELAXED, __HIP_MEMORY_SCOPE_AGENT);
}
__device__ __forceinline__ void coh_sti(int* p, int v) {
  __hip_atomic_store(p, v, __ATOMIC_RELAXED, __HIP_MEMORY_SCOPE_AGENT);
}

// Fence-free flag-tree barrier: __syncthreads drains vmcnt (the block's SC1
// stores are at the coherence point when acked); relaxed flag stores/polls.
// NO release/acquire anywhere -> no buffer_wbl2 / buffer_inv is ever emitted.
__device__ __forceinline__ void grid_barrier(int c, unsigned target) {
  __syncthreads();  // compiler emits s_waitcnt vmcnt(0) before s_barrier
  const int t = threadIdx.x;
  if (t == 0) {
    __hip_atomic_store(&g_arrive[c * 16], target, __ATOMIC_RELAXED,
                       __HIP_MEMORY_SCOPE_AGENT);
  }
  if (c == 0) {
    if (t < NBLK) {
      while (__hip_atomic_load(&g_arrive[t * 16], __ATOMIC_RELAXED,
                               __HIP_MEMORY_SCOPE_AGENT) < target) {
        __builtin_amdgcn_s_sleep(1);
      }
    }
    __syncthreads();
    if (t == 0) {
      __hip_atomic_store(&g_release2, target, __ATOMIC_RELAXED,
                         __HIP_MEMORY_SCOPE_AGENT);
    }
  } else {
    if (t == 0) {
      while (__hip_atomic_load(&g_release2, __ATOMIC_RELAXED,
                               __HIP_MEMORY_SCOPE_AGENT) < target) {
        __builtin_amdgcn_s_sleep(1);
      }
    }
  }
  __syncthreads();
}

// ---------------- host threefry2x32 (exact JAX semantics) -------------------
static inline uint32_t rotl32(uint32_t x, int r) { return (x << r) | (x >> (32 - r)); }

static void threefry2x32(uint32_t k0, uint32_t k1, uint32_t x0, uint32_t x1,
                         uint32_t& o0, uint32_t& o1) {
  const uint32_t ks0 = k0, ks1 = k1, ks2 = k0 ^ k1 ^ 0x1BD11BDAu;
  const int r1[4] = {13, 15, 26, 6}, r2[4] = {17, 29, 16, 24};
  x0 += ks0; x1 += ks1;
  for (int i = 0; i < 4; ++i) { x0 += x1; x1 = rotl32(x1, r1[i]); x1 ^= x0; }
  x0 += ks1; x1 += ks2 + 1u;
  for (int i = 0; i < 4; ++i) { x0 += x1; x1 = rotl32(x1, r2[i]); x1 ^= x0; }
  x0 += ks2; x1 += ks0 + 2u;
  for (int i = 0; i < 4; ++i) { x0 += x1; x1 = rotl32(x1, r1[i]); x1 ^= x0; }
  x0 += ks0; x1 += ks1 + 3u;
  for (int i = 0; i < 4; ++i) { x0 += x1; x1 = rotl32(x1, r2[i]); x1 ^= x0; }
  x0 += ks1; x1 += ks2 + 4u;
  for (int i = 0; i < 4; ++i) { x0 += x1; x1 = rotl32(x1, r1[i]); x1 ^= x0; }
  x0 += ks2; x1 += ks0 + 5u;
  o0 = x0; o1 = x1;
}

struct InitIdx { int v[KC]; };

// jax.random.choice(key(42), 8192, (64,), replace=False)
//  = permutation(key, arange(8192))[:64]  (2-round threefry shuffle)
static InitIdx compute_init_indices() {
  uint32_t k0 = 0u, k1 = 42u;  // jax.random.key(42) -> [0, 42]
  std::vector<int> val(NPTS);
  for (int i = 0; i < NPTS; ++i) val[i] = i;
  std::vector<std::pair<uint32_t, int>> kv(NPTS);
  for (int round = 0; round < 2; ++round) {
    uint32_t nk0, nk1, sk0, sk1;
#if JAX_THREEFRY_PARTITIONABLE
    threefry2x32(k0, k1, 0u, 0u, nk0, nk1);
    threefry2x32(k0, k1, 0u, 1u, sk0, sk1);
    k0 = nk0; k1 = nk1;
    for (int i = 0; i < NPTS; ++i) {
      uint32_t o0, o1;
      threefry2x32(sk0, sk1, 0u, (uint32_t)i, o0, o1);
      kv[i] = std::make_pair(o0 ^ o1, val[i]);
    }
#else
    uint32_t a0, a1, b0, b1;
    threefry2x32(k0, k1, 0u, 2u, a0, a1);
    threefry2x32(k0, k1, 1u, 3u, b0, b1);
    nk0 = a0; nk1 = b0; sk0 = a1; sk1 = b1;
    k0 = nk0; k1 = nk1;
    for (int i = 0; i < NPTS / 2; ++i) {
      uint32_t o0, o1;
      threefry2x32(sk0, sk1, (uint32_t)i, (uint32_t)(i + NPTS / 2), o0, o1);
      kv[i] = std::make_pair(o0, 0);
      kv[i + NPTS / 2] = std::make_pair(o1, 0);
    }
    for (int i = 0; i < NPTS; ++i) kv[i].second = val[i];
#endif
    std::stable_sort(kv.begin(), kv.end(),
                     [](const std::pair<uint32_t, int>& a,
                        const std::pair<uint32_t, int>& b) { return a.first < b.first; });
    for (int i = 0; i < NPTS; ++i) val[i] = kv[i].second;
  }
  InitIdx ii;
  for (int k = 0; k < KC; ++k) ii.v[k] = val[k];
  return ii;
}

// ---------------- kernels ---------------------------------------------------

// Fused R-GEMM + xsq (unchanged).
__global__ void __launch_bounds__(256) k_R_xsq(const float* __restrict__ qk,
                                               const float* __restrict__ W) {
  __shared__ float q[8][DIM];
  const int blk = blockIdx.x;               // 0..1023
  const int b = blk / (LSEQ / 8);
  const int r0 = (blk % (LSEQ / 8)) * 8;
  const int t = threadIdx.x;
  for (int r = 0; r < 8; ++r)
    q[r][t] = qk[((size_t)b * LSEQ + r0 + r) * DIM + t];
  __syncthreads();
  float acc[8] = {0.f, 0.f, 0.f, 0.f, 0.f, 0.f, 0.f, 0.f};
  const float* Wb = W + (size_t)b * DIM * DIM;
  for (int d = 0; d < DIM; ++d) {
    const float w = Wb[d * DIM + t];
#pragma unroll
    for (int r = 0; r < 8; ++r) acc[r] = fmaf(q[r][d], w, acc[r]);
  }
  for (int r = 0; r < 8; ++r)
    g_R[((size_t)b * LSEQ + r0 + r) * DIM + t] = acc[r];
  __syncthreads();
  for (int r = 0; r < 8; ++r) q[r][t] = acc[r];
  __syncthreads();
  const int w = t >> 6, lane = t & 63;
#pragma unroll
  for (int rr = 0; rr < 2; ++rr) {
    const int r = w * 2 + rr;
    const float4 x = *(const float4*)&q[r][lane * 4];
    float s = x.x * x.x + x.y * x.y + x.z * x.z + x.w * x.w;
    for (int o = 32; o > 0; o >>= 1) s += __shfl_xor(s, o);
    if (lane == 0) g_xsq[(size_t)b * LSEQ + r0 + r] = s;
  }
}

// Persistent k-means, 64 blocks x 1024 threads. Mutable cross-block state
// (centT, csq, idx) on relaxed SC1 (coherence point); big read-only data on
// the cached path; fence-free barriers. All fp chains verbatim rounds 4-11
// -> bit-identical trajectory.
__global__ void __launch_bounds__(1024) k_kmeans(InitIdx ii) {
  __shared__ __align__(16) float CsBuf[NCHUNK * PPITCH];  // Cs[d*64+k] in assign; partials [ch][d] in cent
  __shared__ __align__(16) float Xs[64 * XPITCH];         // X tile; aliased as idx_all in cent
  __shared__ float red[256];
  __shared__ int cnt_s[NCHUNK];
  __shared__ unsigned base_s;
  const int t = threadIdx.x;          // 0..1023
  const int c = blockIdx.x;           // chunk 0..63 (also the cluster this block owns)
  const int p0 = c * 128;
  const int plg = t >> 4;             // point 0..63 within current half
  const int cg = t & 15;              // 4-cluster group 0..15
  const int ct = cg * 4;

  if (t == 0)
    base_s = __hip_atomic_load(&g_arrive[c * 16], __ATOMIC_RELAXED,
                               __HIP_MEMORY_SCOPE_AGENT);
  __syncthreads();
  const unsigned base = base_s;
  unsigned bar = 0;

  // ---- init centroid k=c (exact chain, threads 0..255) ----
  float myc = 0.f;
  if (t < 256) {
    const float cv = g_R[(size_t)ii.v[c] * DIM + t];
    myc = cv;
    coh_st(&g_centT[t * KC + c], cv);
    red[t] = cv * cv;
  }
  __syncthreads();
  for (int o = 128; o > 0; o >>= 1) {
    if (t < o) red[t] += red[t + o];
    __syncthreads();
  }
  if (t == 0) coh_st(&g_csq[c], red[0]);
  grid_barrier(c, base + (++bar));

  for (int it = 0; it <= KM_ITERS; ++it) {
    const bool final_pass = (it == KM_ITERS);

    // ---- load Cs from centT (coalesced relaxed SC1; latency hidden by 16
    //      waves/block; LDS writes stride-1 -> 2-way free) ----
    for (int i = t; i < DIM * KC; i += 1024) CsBuf[i] = coh_ld(&g_centT[i]);
    const float cs0 = coh_ld(&g_csq[ct + 0]);
    const float cs1 = coh_ld(&g_csq[ct + 1]);
    const float cs2 = coh_ld(&g_csq[ct + 2]);
    const float cs3 = coh_ld(&g_csq[ct + 3]);

    // ---- assign two 64-point halves: thread = (point, 4-cluster group) ----
    for (int h = 0; h < 2; ++h) {
      __syncthreads();  // protect Xs reuse (and cover Cs load on h==0)
      for (int idx = t; idx < 64 * (DIM / 4); idx += 1024) {
        const int r = idx >> 6;
        const int dq = idx & 63;
        *(float4*)&Xs[r * XPITCH + dq * 4] =
            *(const float4*)(g_R + (size_t)(p0 + h * 64 + r) * DIM + dq * 4);
      }
      __syncthreads();

      // exact per-(point,cluster) fmaf chains (d ascending, same nesting)
      float a0 = 0.f, a1 = 0.f, a2 = 0.f, a3 = 0.f;
#pragma unroll 4
      for (int d = 0; d < DIM; d += 4) {
        const float4 cv0 = *(const float4*)&CsBuf[(d + 0) * 64 + ct];
        const float4 cv1 = *(const float4*)&CsBuf[(d + 1) * 64 + ct];
        const float4 cv2 = *(const float4*)&CsBuf[(d + 2) * 64 + ct];
        const float4 cv3 = *(const float4*)&CsBuf[(d + 3) * 64 + ct];
        const float4 x = *(const float4*)&Xs[plg * XPITCH + d];
        a0 = fmaf(x.x, cv0.x, fmaf(x.y, cv1.x, fmaf(x.z, cv2.x, fmaf(x.w, cv3.x, a0))));
        a1 = fmaf(x.x, cv0.y, fmaf(x.y, cv1.y, fmaf(x.z, cv2.y, fmaf(x.w, cv3.y, a1))));
        a2 = fmaf(x.x, cv0.z, fmaf(x.y, cv1.z, fmaf(x.z, cv2.z, fmaf(x.w, cv3.z, a2))));
        a3 = fmaf(x.x, cv0.w, fmaf(x.y, cv1.w, fmaf(x.z, cv2.w, fmaf(x.w, cv3.w, a3))));
      }

      const int pl = h * 64 + plg;
      const float xs = g_xsq[p0 + pl];
      float best = 3.4e38f;
      int bk = 0;
      {
        float v;
        v = (xs - 2.0f * a0) + cs0; if (v < best) { best = v; bk = ct + 0; }
        v = (xs - 2.0f * a1) + cs1; if (v < best) { best = v; bk = ct + 1; }
        v = (xs - 2.0f * a2) + cs2; if (v < best) { best = v; bk = ct + 2; }
        v = (xs - 2.0f * a3) + cs3; if (v < best) { best = v; bk = ct + 3; }
      }
      // same 16-lane butterfly (lanes = cg 0..15 for this point), same inputs
#pragma unroll
      for (int o = 1; o < 16; o <<= 1) {
        const float ov = __shfl_xor(best, o);
        const int obk = __shfl_xor(bk, o);
        if (ov < best || (ov == best && obk < bk)) { best = ov; bk = obk; }
      }
      if (cg == 0) coh_sti(&g_idx[p0 + pl], bk);   // publish every iteration
    }
    if (final_pass) break;
    grid_barrier(c, base + (++bar));  // A: all assignments at coherence point

    // ---- cent phase: block c computes centroid c (exact chunked chains) ----
    {
      // load all 8192 assignments into LDS (coalesced relaxed SC1)
      int* idxa = (int*)Xs;
      for (int i = t; i < NPTS; i += 1024) idxa[i] = coh_ldi(&g_idx[i]);
      __syncthreads();

      // thread (ch, dq): chunk ch's partial for cluster c, dims dq*16..+15,
      // ascending p within chunk — identical chain to the old upA.
      const int ch = t >> 4;
      const int dq = t & 15;
      float4 s[4];
#pragma unroll
      for (int q = 0; q < 4; ++q) s[q] = make_float4(0.f, 0.f, 0.f, 0.f);
      int cnt = 0;
      const int pb = ch * 128;
      for (int j = 0; j < 128; ++j) {
        if (idxa[pb + j] == c) {
          const float4* row = (const float4*)(g_R + (size_t)(pb + j) * DIM) + dq * 4;
#pragma unroll
          for (int q = 0; q < 4; ++q) {
            const float4 x = row[q];
            s[q].x += x.x; s[q].y += x.y; s[q].z += x.z; s[q].w += x.w;
          }
          ++cnt;
        }
      }
      // stage partials in LDS (CsBuf free since assign ended at barrier A)
      float* part = CsBuf;  // layout part[ch*PPITCH + d]
#pragma unroll
      for (int q = 0; q < 4; ++q)
        *(float4*)&part[ch * PPITCH + dq * 16 + q * 4] = s[q];
      if (dq == 0) cnt_s[ch] = cnt;
      __syncthreads();

      // combine in exact ascending chunk order (old upB chain), divide, csq
      if (t < 256) {
        float ssum = 0.f;
#pragma unroll 4
        for (int c2 = 0; c2 < NCHUNK; ++c2) ssum += part[c2 * PPITCH + t];
        int ctot = 0;
#pragma unroll 4
        for (int c2 = 0; c2 < NCHUNK; ++c2) ctot += cnt_s[c2];
        const float nc = (ctot > 0) ? (ssum / (float)ctot) : myc;
        myc = nc;
        coh_st(&g_centT[t * KC + c], nc);
        red[t] = nc * nc;
      }
      __syncthreads();
      for (int o = 128; o > 0; o >>= 1) {
        if (t < o) red[t] += red[t + o];
        __syncthreads();
      }
      if (t == 0) coh_st(&g_csq[c], red[0]);
    }
    grid_barrier(c, base + (++bar));  // B: new centroids at coherence point
  }
}

// mask write: out[b,h,i,j] = (cid[b,i]==cid[b,j]) ? 0 : -10000. 16 rows/block.
__global__ void __launch_bounds__(256) k_mask(float* __restrict__ out, int H) {
  const int blk = blockIdx.x;
  const int tiles = LSEQ / 16;  // 256
  const int b = blk / (H * tiles);
  const int h = (blk / tiles) % H;
  const int tile = blk % tiles;
  const int t = threadIdx.x;
  __shared__ int cid[LSEQ];  // 16 KB
  for (int j = t; j < LSEQ; j += 256) cid[j] = g_idx[b * LSEQ + j];
  __syncthreads();
  const size_t base = ((size_t)(b * H + h) * LSEQ + (size_t)tile * 16) * LSEQ;
  for (int r = 0; r < 16; ++r) {
    const int my = cid[tile * 16 + r];
    float4* orow = (float4*)(out + base + (size_t)r * LSEQ);
#pragma unroll
    for (int s = 0; s < 4; ++s) {
      const int c4 = s * 256 + t;
      const int j = c4 * 4;
      float4 v;
      v.x = (cid[j + 0] == my) ? 0.f : -10000.f;
      v.y = (cid[j + 1] == my) ? 0.f : -10000.f;
      v.z = (cid[j + 2] == my) ? 0.f : -10000.f;
      v.w = (cid[j + 3] == my) ? 0.f : -10000.f;
      orow[c4] = v;
    }
  }
}

// ---------------- launch -----------------------------------------------------
extern "C" void kernel_launch(void* const* d_in, const int* in_sizes, int n_in,
                              void* d_out, int out_size, void* d_ws, size_t ws_size,
                              hipStream_t stream) {
  const float* qk = (const float*)d_in[0];
  const float* W = (const float*)d_in[1];
  const int H = out_size / (NB * LSEQ * LSEQ);  // 8

  const InitIdx ii = compute_init_indices();  // pure host integer math

  k_R_xsq<<<NB * (LSEQ / 8), 256, 0, stream>>>(qk, W);
  k_kmeans<<<NBLK, 1024, 0, stream>>>(ii);
  k_mask<<<NB * H * (LSEQ / 16), 256, 0, stream>>>((float*)d_out, H);
}

// Round 13
// 720.850 us; speedup vs baseline: 1.0496x; 1.0496x over previous
//
#include <hip/hip_runtime.h>
#include <stdint.h>
#include <stddef.h>
#include <vector>
#include <algorithm>
#include <utility>

// Problem constants (B=2, L=4096, D=256, H=8, K=sqrt(L)=64, 10 Lloyd iters)
#define NPTS 8192
#define DIM  256
#define KC   64
#define LSEQ 4096
#define NB   2
#define KM_ITERS 10
#define NCHUNK 64     // 8192/128 points per summation chunk (bit-exact structure)
#define NBLK 64       // persistent kmeans blocks (block = chunk = cluster)
#define XPITCH 260    // padded LDS row for X tile (1040 B, 16B-aligned rows)
#define PPITCH 257    // padded LDS row for chunk-partials

// JAX threefry mode: 1 = partitionable (default since jax 0.4.36), 0 = original
#define JAX_THREEFRY_PARTITIONABLE 1

// ---------------- static device scratch (fully rewritten every call) --------
__device__ float g_R[NPTS * DIM];          // 8 MB   rotated points (read-only in kmeans)
__device__ float g_xsq[NPTS];              // 32 KB  per-point squared norm
__device__ float g_centT[DIM * KC];        // 64 KB  centroids transposed [d][k]
__device__ float g_csq[KC];                // per-centroid squared norm
__device__ int   g_idx[NPTS];              // assignments (every iter; final = cid)

// Flag-tree grid barrier state (monotone across graph replays; each block
// reads its own flag at entry as base — deterministic per replay).
__device__ unsigned g_arrive[NBLK * 16];   // block c uses g_arrive[c*16]
__device__ unsigned g_release2;            // release word (monotone)

// Round-7/11 barrier (best measured): arrival release-store (one L2 wb),
// block-0 parallel relaxed polls, single release store + acquire-inv.
__device__ __forceinline__ void grid_barrier(int c, unsigned target) {
  __syncthreads();
  const int t = threadIdx.x;
  if (t == 0) {
    __hip_atomic_store(&g_arrive[c * 16], target, __ATOMIC_RELEASE,
                       __HIP_MEMORY_SCOPE_AGENT);
  }
  if (c == 0) {
    if (t < NBLK) {
      while (__hip_atomic_load(&g_arrive[t * 16], __ATOMIC_RELAXED,
                               __HIP_MEMORY_SCOPE_AGENT) < target) {
        __builtin_amdgcn_s_sleep(1);
      }
    }
    __syncthreads();
    if (t == 0) {
      __hip_atomic_store(&g_release2, target, __ATOMIC_RELEASE,
                         __HIP_MEMORY_SCOPE_AGENT);
      (void)__hip_atomic_load(&g_release2, __ATOMIC_ACQUIRE,
                              __HIP_MEMORY_SCOPE_AGENT);  // single inv
    }
  } else {
    if (t == 0) {
      while (__hip_atomic_load(&g_release2, __ATOMIC_RELAXED,
                               __HIP_MEMORY_SCOPE_AGENT) < target) {
        __builtin_amdgcn_s_sleep(2);
      }
      (void)__hip_atomic_load(&g_release2, __ATOMIC_ACQUIRE,
                              __HIP_MEMORY_SCOPE_AGENT);  // single inv
    }
  }
  __syncthreads();
}

// ---------------- host threefry2x32 (exact JAX semantics) -------------------
static inline uint32_t rotl32(uint32_t x, int r) { return (x << r) | (x >> (32 - r)); }

static void threefry2x32(uint32_t k0, uint32_t k1, uint32_t x0, uint32_t x1,
                         uint32_t& o0, uint32_t& o1) {
  const uint32_t ks0 = k0, ks1 = k1, ks2 = k0 ^ k1 ^ 0x1BD11BDAu;
  const int r1[4] = {13, 15, 26, 6}, r2[4] = {17, 29, 16, 24};
  x0 += ks0; x1 += ks1;
  for (int i = 0; i < 4; ++i) { x0 += x1; x1 = rotl32(x1, r1[i]); x1 ^= x0; }
  x0 += ks1; x1 += ks2 + 1u;
  for (int i = 0; i < 4; ++i) { x0 += x1; x1 = rotl32(x1, r2[i]); x1 ^= x0; }
  x0 += ks2; x1 += ks0 + 2u;
  for (int i = 0; i < 4; ++i) { x0 += x1; x1 = rotl32(x1, r1[i]); x1 ^= x0; }
  x0 += ks0; x1 += ks1 + 3u;
  for (int i = 0; i < 4; ++i) { x0 += x1; x1 = rotl32(x1, r2[i]); x1 ^= x0; }
  x0 += ks1; x1 += ks2 + 4u;
  for (int i = 0; i < 4; ++i) { x0 += x1; x1 = rotl32(x1, r1[i]); x1 ^= x0; }
  x0 += ks2; x1 += ks0 + 5u;
  o0 = x0; o1 = x1;
}

struct InitIdx { int v[KC]; };

// jax.random.choice(key(42), 8192, (64,), replace=False)
//  = permutation(key, arange(8192))[:64]  (2-round threefry shuffle)
static InitIdx compute_init_indices() {
  uint32_t k0 = 0u, k1 = 42u;  // jax.random.key(42) -> [0, 42]
  std::vector<int> val(NPTS);
  for (int i = 0; i < NPTS; ++i) val[i] = i;
  std::vector<std::pair<uint32_t, int>> kv(NPTS);
  for (int round = 0; round < 2; ++round) {
    uint32_t nk0, nk1, sk0, sk1;
#if JAX_THREEFRY_PARTITIONABLE
    threefry2x32(k0, k1, 0u, 0u, nk0, nk1);
    threefry2x32(k0, k1, 0u, 1u, sk0, sk1);
    k0 = nk0; k1 = nk1;
    for (int i = 0; i < NPTS; ++i) {
      uint32_t o0, o1;
      threefry2x32(sk0, sk1, 0u, (uint32_t)i, o0, o1);
      kv[i] = std::make_pair(o0 ^ o1, val[i]);
    }
#else
    uint32_t a0, a1, b0, b1;
    threefry2x32(k0, k1, 0u, 2u, a0, a1);
    threefry2x32(k0, k1, 1u, 3u, b0, b1);
    nk0 = a0; nk1 = b0; sk0 = a1; sk1 = b1;
    k0 = nk0; k1 = nk1;
    for (int i = 0; i < NPTS / 2; ++i) {
      uint32_t o0, o1;
      threefry2x32(sk0, sk1, (uint32_t)i, (uint32_t)(i + NPTS / 2), o0, o1);
      kv[i] = std::make_pair(o0, 0);
      kv[i + NPTS / 2] = std::make_pair(o1, 0);
    }
    for (int i = 0; i < NPTS; ++i) kv[i].second = val[i];
#endif
    std::stable_sort(kv.begin(), kv.end(),
                     [](const std::pair<uint32_t, int>& a,
                        const std::pair<uint32_t, int>& b) { return a.first < b.first; });
    for (int i = 0; i < NPTS; ++i) val[i] = kv[i].second;
  }
  InitIdx ii;
  for (int k = 0; k < KC; ++k) ii.v[k] = val[k];
  return ii;
}

// ---------------- kernels ---------------------------------------------------

// Fused R-GEMM + xsq (unchanged).
__global__ void __launch_bounds__(256) k_R_xsq(const float* __restrict__ qk,
                                               const float* __restrict__ W) {
  __shared__ float q[8][DIM];
  const int blk = blockIdx.x;               // 0..1023
  const int b = blk / (LSEQ / 8);
  const int r0 = (blk % (LSEQ / 8)) * 8;
  const int t = threadIdx.x;
  for (int r = 0; r < 8; ++r)
    q[r][t] = qk[((size_t)b * LSEQ + r0 + r) * DIM + t];
  __syncthreads();
  float acc[8] = {0.f, 0.f, 0.f, 0.f, 0.f, 0.f, 0.f, 0.f};
  const float* Wb = W + (size_t)b * DIM * DIM;
  for (int d = 0; d < DIM; ++d) {
    const float w = Wb[d * DIM + t];
#pragma unroll
    for (int r = 0; r < 8; ++r) acc[r] = fmaf(q[r][d], w, acc[r]);
  }
  for (int r = 0; r < 8; ++r)
    g_R[((size_t)b * LSEQ + r0 + r) * DIM + t] = acc[r];
  __syncthreads();
  for (int r = 0; r < 8; ++r) q[r][t] = acc[r];
  __syncthreads();
  const int w = t >> 6, lane = t & 63;
#pragma unroll
  for (int rr = 0; rr < 2; ++rr) {
    const int r = w * 2 + rr;
    const float4 x = *(const float4*)&q[r][lane * 4];
    float s = x.x * x.x + x.y * x.y + x.z * x.z + x.w * x.w;
    for (int o = 32; o > 0; o >>= 1) s += __shfl_xor(s, o);
    if (lane == 0) g_xsq[(size_t)b * LSEQ + r0 + r] = s;
  }
}

// Persistent k-means, 64 blocks x 1024 threads. Assign computed by threads
// t<256 with the ROUND-4 P4C4 register tile (64 fmaf per 8 ds_read_b128 —
// 2.5x fewer LDS instructions than the P1C4 mapping; LDS pipe was the
// bottleneck). All fp chains verbatim round 4 -> bit-identical trajectory.
__global__ void __launch_bounds__(1024) k_kmeans(InitIdx ii) {
  __shared__ __align__(16) float CsBuf[NCHUNK * PPITCH];  // Cs[d*64+k] in assign; partials in cent
  __shared__ __align__(16) float Xs[64 * XPITCH];         // X tile; aliased as idx_all in cent
  __shared__ float red[256];
  __shared__ int cnt_s[NCHUNK];
  __shared__ unsigned base_s;
  const int t = threadIdx.x;          // 0..1023
  const int c = blockIdx.x;           // chunk 0..63 (also the cluster this block owns)
  const int p0 = c * 128;
  const int ptg = t >> 4;             // for t<256: 4-point group 0..15
  const int ctg = t & 15;             // 4-cluster group 0..15
  const int ct = ctg * 4;

  if (t == 0)
    base_s = __hip_atomic_load(&g_arrive[c * 16], __ATOMIC_RELAXED,
                               __HIP_MEMORY_SCOPE_AGENT);
  __syncthreads();
  const unsigned base = base_s;
  unsigned bar = 0;

  // ---- init centroid k=c (exact chain, threads 0..255) ----
  float myc = 0.f;
  if (t < 256) {
    const float cv = g_R[(size_t)ii.v[c] * DIM + t];
    myc = cv;
    g_centT[t * KC + c] = cv;
    red[t] = cv * cv;
  }
  __syncthreads();
  for (int o = 128; o > 0; o >>= 1) {
    if (t < o) red[t] += red[t + o];
    __syncthreads();
  }
  if (t == 0) g_csq[c] = red[0];
  grid_barrier(c, base + (++bar));

  for (int it = 0; it <= KM_ITERS; ++it) {
    const bool final_pass = (it == KM_ITERS);

    // ---- load Cs from centT (coalesced cached loads; fresh after barrier) --
    {
      float4* Cs4 = (float4*)CsBuf;
      const float4* T4 = (const float4*)g_centT;
      for (int i = t; i < (DIM * KC) / 4; i += 1024) Cs4[i] = T4[i];
    }
    const float cs0 = g_csq[ct + 0];
    const float cs1 = g_csq[ct + 1];
    const float cs2 = g_csq[ct + 2];
    const float cs3 = g_csq[ct + 3];

    // ---- assign two 64-point halves; threads t<256, P=4 x C=4 tile ----
    for (int h = 0; h < 2; ++h) {
      __syncthreads();  // protect Xs reuse (and cover Cs load on h==0)
      for (int idx = t; idx < 64 * (DIM / 4); idx += 1024) {
        const int r = idx >> 6;
        const int dq = idx & 63;
        *(float4*)&Xs[r * XPITCH + dq * 4] =
            *(const float4*)(g_R + (size_t)(p0 + h * 64 + r) * DIM + dq * 4);
      }
      __syncthreads();

      if (t < 256) {
        // exact round-4 fmaf chains (d ascending, same nesting per (p,k))
        float acc[4][4];
#pragma unroll
        for (int r = 0; r < 4; ++r)
#pragma unroll
          for (int j = 0; j < 4; ++j) acc[r][j] = 0.f;

#pragma unroll 4
        for (int d = 0; d < DIM; d += 4) {
          const float4 cv0 = *(const float4*)&CsBuf[(d + 0) * 64 + ct];
          const float4 cv1 = *(const float4*)&CsBuf[(d + 1) * 64 + ct];
          const float4 cv2 = *(const float4*)&CsBuf[(d + 2) * 64 + ct];
          const float4 cv3 = *(const float4*)&CsBuf[(d + 3) * 64 + ct];
#pragma unroll
          for (int r = 0; r < 4; ++r) {
            const float4 x = *(const float4*)&Xs[(ptg * 4 + r) * XPITCH + d];
            acc[r][0] = fmaf(x.x, cv0.x, fmaf(x.y, cv1.x, fmaf(x.z, cv2.x, fmaf(x.w, cv3.x, acc[r][0]))));
            acc[r][1] = fmaf(x.x, cv0.y, fmaf(x.y, cv1.y, fmaf(x.z, cv2.y, fmaf(x.w, cv3.y, acc[r][1]))));
            acc[r][2] = fmaf(x.x, cv0.z, fmaf(x.y, cv1.z, fmaf(x.z, cv2.z, fmaf(x.w, cv3.z, acc[r][2]))));
            acc[r][3] = fmaf(x.x, cv0.w, fmaf(x.y, cv1.w, fmaf(x.z, cv2.w, fmaf(x.w, cv3.w, acc[r][3]))));
          }
        }

#pragma unroll
        for (int r = 0; r < 4; ++r) {
          const int pl = h * 64 + ptg * 4 + r;
          const float xs = g_xsq[p0 + pl];
          float best = 3.4e38f;
          int bk = 0;
          {
            float v;
            v = (xs - 2.0f * acc[r][0]) + cs0; if (v < best) { best = v; bk = ct + 0; }
            v = (xs - 2.0f * acc[r][1]) + cs1; if (v < best) { best = v; bk = ct + 1; }
            v = (xs - 2.0f * acc[r][2]) + cs2; if (v < best) { best = v; bk = ct + 2; }
            v = (xs - 2.0f * acc[r][3]) + cs3; if (v < best) { best = v; bk = ct + 3; }
          }
          // same 16-lane butterfly (lanes = ctg within wave), same inputs
#pragma unroll
          for (int o = 1; o < 16; o <<= 1) {
            const float ov = __shfl_xor(best, o);
            const int obk = __shfl_xor(bk, o);
            if (ov < best || (ov == best && obk < bk)) { best = ov; bk = obk; }
          }
          if (ctg == 0) g_idx[p0 + pl] = bk;   // publish every iteration
        }
      }
    }
    if (final_pass) break;
    grid_barrier(c, base + (++bar));  // A: all assignments visible

    // ---- cent phase: block c computes centroid c (exact chunked chains) ----
    {
      // load all 8192 assignments into LDS (overlay on Xs)
      int* idxa = (int*)Xs;
      {
        int4* dst = (int4*)idxa;
        const int4* src = (const int4*)g_idx;
        for (int i = t; i < NPTS / 4; i += 1024) dst[i] = src[i];
      }
      __syncthreads();

      // thread (ch, dq): chunk ch's partial for cluster c, dims dq*16..+15,
      // ascending p within chunk — identical chain to the old upA.
      const int ch = t >> 4;
      const int dq = t & 15;
      float4 s[4];
#pragma unroll
      for (int q = 0; q < 4; ++q) s[q] = make_float4(0.f, 0.f, 0.f, 0.f);
      int cnt = 0;
      const int pb = ch * 128;
      for (int j4 = 0; j4 < 32; ++j4) {
        const int4 iv = *(const int4*)&idxa[pb + j4 * 4];
        // ascending j within the quad — identical order/conditions
        if (iv.x == c) {
          const float4* row = (const float4*)(g_R + (size_t)(pb + j4 * 4 + 0) * DIM) + dq * 4;
#pragma unroll
          for (int q = 0; q < 4; ++q) { const float4 x = row[q]; s[q].x += x.x; s[q].y += x.y; s[q].z += x.z; s[q].w += x.w; }
          ++cnt;
        }
        if (iv.y == c) {
          const float4* row = (const float4*)(g_R + (size_t)(pb + j4 * 4 + 1) * DIM) + dq * 4;
#pragma unroll
          for (int q = 0; q < 4; ++q) { const float4 x = row[q]; s[q].x += x.x; s[q].y += x.y; s[q].z += x.z; s[q].w += x.w; }
          ++cnt;
        }
        if (iv.z == c) {
          const float4* row = (const float4*)(g_R + (size_t)(pb + j4 * 4 + 2) * DIM) + dq * 4;
#pragma unroll
          for (int q = 0; q < 4; ++q) { const float4 x = row[q]; s[q].x += x.x; s[q].y += x.y; s[q].z += x.z; s[q].w += x.w; }
          ++cnt;
        }
        if (iv.w == c) {
          const float4* row = (const float4*)(g_R + (size_t)(pb + j4 * 4 + 3) * DIM) + dq * 4;
#pragma unroll
          for (int q = 0; q < 4; ++q) { const float4 x = row[q]; s[q].x += x.x; s[q].y += x.y; s[q].z += x.z; s[q].w += x.w; }
          ++cnt;
        }
      }
      // stage partials in LDS (CsBuf free since assign ended at barrier A)
      float* part = CsBuf;  // layout part[ch*PPITCH + d]
#pragma unroll
      for (int q = 0; q < 4; ++q)
        *(float4*)&part[ch * PPITCH + dq * 16 + q * 4] = s[q];
      if (dq == 0) cnt_s[ch] = cnt;
      __syncthreads();

      // combine in exact ascending chunk order (old upB chain), divide, csq
      if (t < 256) {
        float ssum = 0.f;
#pragma unroll 4
        for (int c2 = 0; c2 < NCHUNK; ++c2) ssum += part[c2 * PPITCH + t];
        int ctot = 0;
#pragma unroll 4
        for (int c2 = 0; c2 < NCHUNK; ++c2) ctot += cnt_s[c2];
        const float nc = (ctot > 0) ? (ssum / (float)ctot) : myc;
        myc = nc;
        g_centT[t * KC + c] = nc;
        red[t] = nc * nc;
      }
      __syncthreads();
      for (int o = 128; o > 0; o >>= 1) {
        if (t < o) red[t] += red[t + o];
        __syncthreads();
      }
      if (t == 0) g_csq[c] = red[0];
    }
    grid_barrier(c, base + (++bar));  // B: new centroids visible
  }
}

// mask write: out[b,h,i,j] = (cid[b,i]==cid[b,j]) ? 0 : -10000. 16 rows/block.
__global__ void __launch_bounds__(256) k_mask(float* __restrict__ out, int H) {
  const int blk = blockIdx.x;
  const int tiles = LSEQ / 16;  // 256
  const int b = blk / (H * tiles);
  const int h = (blk / tiles) % H;
  const int tile = blk % tiles;
  const int t = threadIdx.x;
  __shared__ int cid[LSEQ];  // 16 KB
  for (int j = t; j < LSEQ; j += 256) cid[j] = g_idx[b * LSEQ + j];
  __syncthreads();
  const size_t base = ((size_t)(b * H + h) * LSEQ + (size_t)tile * 16) * LSEQ;
  for (int r = 0; r < 16; ++r) {
    const int my = cid[tile * 16 + r];
    float4* orow = (float4*)(out + base + (size_t)r * LSEQ);
#pragma unroll
    for (int s = 0; s < 4; ++s) {
      const int c4 = s * 256 + t;
      const int j = c4 * 4;
      float4 v;
      v.x = (cid[j + 0] == my) ? 0.f : -10000.f;
      v.y = (cid[j + 1] == my) ? 0.f : -10000.f;
      v.z = (cid[j + 2] == my) ? 0.f : -10000.f;
      v.w = (cid[j + 3] == my) ? 0.f : -10000.f;
      orow[c4] = v;
    }
  }
}

// ---------------- launch -----------------------------------------------------
extern "C" void kernel_launch(void* const* d_in, const int* in_sizes, int n_in,
                              void* d_out, int out_size, void* d_ws, size_t ws_size,
                              hipStream_t stream) {
  const float* qk = (const float*)d_in[0];
  const float* W = (const float*)d_in[1];
  const int H = out_size / (NB * LSEQ * LSEQ);  // 8

  const InitIdx ii = compute_init_indices();  // pure host integer math

  k_R_xsq<<<NB * (LSEQ / 8), 256, 0, stream>>>(qk, W);
  k_kmeans<<<NBLK, 1024, 0, stream>>>(ii);
  k_mask<<<NB * H * (LSEQ / 16), 256, 0, stream>>>((float*)d_out, H);
}

// Round 14
// 715.340 us; speedup vs baseline: 1.0577x; 1.0077x over previous
//
#include <hip/hip_runtime.h>
#include <stdint.h>
#include <stddef.h>
#include <vector>
#include <algorithm>
#include <utility>

// Problem constants (B=2, L=4096, D=256, H=8, K=sqrt(L)=64, 10 Lloyd iters)
#define NPTS 8192
#define DIM  256
#define KC   64
#define LSEQ 4096
#define NB   2
#define KM_ITERS 10
#define NCHUNK 64     // 8192/128 points per summation chunk (bit-exact structure)
#define NBLK 64       // persistent kmeans blocks (block = chunk = cluster)
#define XPITCH 260    // padded LDS row for X tile (1040 B, 16B-aligned rows)
#define PPITCH 257    // padded LDS row for chunk-partials

// JAX threefry mode: 1 = partitionable (default since jax 0.4.36), 0 = original
#define JAX_THREEFRY_PARTITIONABLE 1

// ---------------- static device scratch (fully rewritten every call) --------
__device__ float g_R[NPTS * DIM];          // 8 MB   rotated points (read-only in kmeans)
__device__ float g_xsq[NPTS];              // 32 KB  per-point squared norm
__device__ float g_centT[DIM * KC];        // 64 KB  centroids transposed [d][k]
__device__ float g_csq[KC];                // per-centroid squared norm
__device__ int   g_idx[NPTS];              // assignments (every iter; final = cid)

// Barrier state (monotone across graph replays; each block reads its own
// arrival flag at entry as base — deterministic per replay).
// KEY CHANGE vs rounds 4-13: per-block PADDED RELEASE LINES. Every previous
// barrier had 63 blocks polling ONE release word — the L3 line's bank
// serializes 63 concurrent pollers and the leader's release store queues
// behind them (multi-us propagation). Now: one poller per line.
__device__ unsigned g_arrive[NBLK * 16];       // block c arrives on g_arrive[c*16]
__device__ unsigned g_release_arr[NBLK * 16];  // block c polls g_release_arr[c*16]

__device__ __forceinline__ void grid_barrier(int c, unsigned target) {
  __syncthreads();
  const int t = threadIdx.x;
  if (t == 0) {
    // release: publishes this block's prior writes (one L2 wb)
    __hip_atomic_store(&g_arrive[c * 16], target, __ATOMIC_RELEASE,
                       __HIP_MEMORY_SCOPE_AGENT);
  }
  if (c == 0) {
    // leader: wave 0 polls the 64 arrival lines in parallel (1 poller/line)
    if (t < NBLK) {
      while (__hip_atomic_load(&g_arrive[t * 16], __ATOMIC_RELAXED,
                               __HIP_MEMORY_SCOPE_AGENT) < target) {
        __builtin_amdgcn_s_sleep(1);
      }
    }
    __syncthreads();
    if (t < NBLK) {
      if (t == 0) {
        // acquire-fence: pairs with all 64 arrival release-stores (one inv)
        __builtin_amdgcn_fence(__ATOMIC_ACQUIRE, "agent");
        // release-fence before the fanout stores (one wb)
        __builtin_amdgcn_fence(__ATOMIC_RELEASE, "agent");
      }
      // fanout: one wave instruction, 64 separate padded lines (no contention)
      __hip_atomic_store(&g_release_arr[t * 16], target, __ATOMIC_RELAXED,
                         __HIP_MEMORY_SCOPE_AGENT);
    }
  } else {
    if (t == 0) {
      // poll OWN padded line: exactly one poller per L3 line
      while (__hip_atomic_load(&g_release_arr[c * 16], __ATOMIC_RELAXED,
                               __HIP_MEMORY_SCOPE_AGENT) < target) {
        __builtin_amdgcn_s_sleep(1);
      }
      // acquire-fence: transitively pairs leader's release-fence -> all data
      __builtin_amdgcn_fence(__ATOMIC_ACQUIRE, "agent");
    }
  }
  __syncthreads();
}

// ---------------- host threefry2x32 (exact JAX semantics) -------------------
static inline uint32_t rotl32(uint32_t x, int r) { return (x << r) | (x >> (32 - r)); }

static void threefry2x32(uint32_t k0, uint32_t k1, uint32_t x0, uint32_t x1,
                         uint32_t& o0, uint32_t& o1) {
  const uint32_t ks0 = k0, ks1 = k1, ks2 = k0 ^ k1 ^ 0x1BD11BDAu;
  const int r1[4] = {13, 15, 26, 6}, r2[4] = {17, 29, 16, 24};
  x0 += ks0; x1 += ks1;
  for (int i = 0; i < 4; ++i) { x0 += x1; x1 = rotl32(x1, r1[i]); x1 ^= x0; }
  x0 += ks1; x1 += ks2 + 1u;
  for (int i = 0; i < 4; ++i) { x0 += x1; x1 = rotl32(x1, r2[i]); x1 ^= x0; }
  x0 += ks2; x1 += ks0 + 2u;
  for (int i = 0; i < 4; ++i) { x0 += x1; x1 = rotl32(x1, r1[i]); x1 ^= x0; }
  x0 += ks0; x1 += ks1 + 3u;
  for (int i = 0; i < 4; ++i) { x0 += x1; x1 = rotl32(x1, r2[i]); x1 ^= x0; }
  x0 += ks1; x1 += ks2 + 4u;
  for (int i = 0; i < 4; ++i) { x0 += x1; x1 = rotl32(x1, r1[i]); x1 ^= x0; }
  x0 += ks2; x1 += ks0 + 5u;
  o0 = x0; o1 = x1;
}

struct InitIdx { int v[KC]; };

// jax.random.choice(key(42), 8192, (64,), replace=False)
//  = permutation(key, arange(8192))[:64]  (2-round threefry shuffle)
static InitIdx compute_init_indices() {
  uint32_t k0 = 0u, k1 = 42u;  // jax.random.key(42) -> [0, 42]
  std::vector<int> val(NPTS);
  for (int i = 0; i < NPTS; ++i) val[i] = i;
  std::vector<std::pair<uint32_t, int>> kv(NPTS);
  for (int round = 0; round < 2; ++round) {
    uint32_t nk0, nk1, sk0, sk1;
#if JAX_THREEFRY_PARTITIONABLE
    threefry2x32(k0, k1, 0u, 0u, nk0, nk1);
    threefry2x32(k0, k1, 0u, 1u, sk0, sk1);
    k0 = nk0; k1 = nk1;
    for (int i = 0; i < NPTS; ++i) {
      uint32_t o0, o1;
      threefry2x32(sk0, sk1, 0u, (uint32_t)i, o0, o1);
      kv[i] = std::make_pair(o0 ^ o1, val[i]);
    }
#else
    uint32_t a0, a1, b0, b1;
    threefry2x32(k0, k1, 0u, 2u, a0, a1);
    threefry2x32(k0, k1, 1u, 3u, b0, b1);
    nk0 = a0; nk1 = b0; sk0 = a1; sk1 = b1;
    k0 = nk0; k1 = nk1;
    for (int i = 0; i < NPTS / 2; ++i) {
      uint32_t o0, o1;
      threefry2x32(sk0, sk1, (uint32_t)i, (uint32_t)(i + NPTS / 2), o0, o1);
      kv[i] = std::make_pair(o0, 0);
      kv[i + NPTS / 2] = std::make_pair(o1, 0);
    }
    for (int i = 0; i < NPTS; ++i) kv[i].second = val[i];
#endif
    std::stable_sort(kv.begin(), kv.end(),
                     [](const std::pair<uint32_t, int>& a,
                        const std::pair<uint32_t, int>& b) { return a.first < b.first; });
    for (int i = 0; i < NPTS; ++i) val[i] = kv[i].second;
  }
  InitIdx ii;
  for (int k = 0; k < KC; ++k) ii.v[k] = val[k];
  return ii;
}

// ---------------- kernels ---------------------------------------------------

// Fused R-GEMM + xsq (unchanged).
__global__ void __launch_bounds__(256) k_R_xsq(const float* __restrict__ qk,
                                               const float* __restrict__ W) {
  __shared__ float q[8][DIM];
  const int blk = blockIdx.x;               // 0..1023
  const int b = blk / (LSEQ / 8);
  const int r0 = (blk % (LSEQ / 8)) * 8;
  const int t = threadIdx.x;
  for (int r = 0; r < 8; ++r)
    q[r][t] = qk[((size_t)b * LSEQ + r0 + r) * DIM + t];
  __syncthreads();
  float acc[8] = {0.f, 0.f, 0.f, 0.f, 0.f, 0.f, 0.f, 0.f};
  const float* Wb = W + (size_t)b * DIM * DIM;
  for (int d = 0; d < DIM; ++d) {
    const float w = Wb[d * DIM + t];
#pragma unroll
    for (int r = 0; r < 8; ++r) acc[r] = fmaf(q[r][d], w, acc[r]);
  }
  for (int r = 0; r < 8; ++r)
    g_R[((size_t)b * LSEQ + r0 + r) * DIM + t] = acc[r];
  __syncthreads();
  for (int r = 0; r < 8; ++r) q[r][t] = acc[r];
  __syncthreads();
  const int w = t >> 6, lane = t & 63;
#pragma unroll
  for (int rr = 0; rr < 2; ++rr) {
    const int r = w * 2 + rr;
    const float4 x = *(const float4*)&q[r][lane * 4];
    float s = x.x * x.x + x.y * x.y + x.z * x.z + x.w * x.w;
    for (int o = 32; o > 0; o >>= 1) s += __shfl_xor(s, o);
    if (lane == 0) g_xsq[(size_t)b * LSEQ + r0 + r] = s;
  }
}

// Persistent k-means, 64 blocks x 1024 threads. Assign = round-4 P4C4 tile
// (threads t<256). All fp chains verbatim round 4 -> bit-identical trajectory.
__global__ void __launch_bounds__(1024) k_kmeans(InitIdx ii) {
  __shared__ __align__(16) float CsBuf[NCHUNK * PPITCH];  // Cs[d*64+k] in assign; partials in cent
  __shared__ __align__(16) float Xs[64 * XPITCH];         // X tile; aliased as idx_all in cent
  __shared__ float red[256];
  __shared__ int cnt_s[NCHUNK];
  __shared__ unsigned base_s;
  const int t = threadIdx.x;          // 0..1023
  const int c = blockIdx.x;           // chunk 0..63 (also the cluster this block owns)
  const int p0 = c * 128;
  const int ptg = t >> 4;             // for t<256: 4-point group 0..15
  const int ctg = t & 15;             // 4-cluster group 0..15
  const int ct = ctg * 4;

  if (t == 0)
    base_s = __hip_atomic_load(&g_arrive[c * 16], __ATOMIC_RELAXED,
                               __HIP_MEMORY_SCOPE_AGENT);
  __syncthreads();
  const unsigned base = base_s;
  unsigned bar = 0;

  // ---- init centroid k=c (exact chain, threads 0..255) ----
  float myc = 0.f;
  if (t < 256) {
    const float cv = g_R[(size_t)ii.v[c] * DIM + t];
    myc = cv;
    g_centT[t * KC + c] = cv;
    red[t] = cv * cv;
  }
  __syncthreads();
  for (int o = 128; o > 0; o >>= 1) {
    if (t < o) red[t] += red[t + o];
    __syncthreads();
  }
  if (t == 0) g_csq[c] = red[0];
  grid_barrier(c, base + (++bar));

  for (int it = 0; it <= KM_ITERS; ++it) {
    const bool final_pass = (it == KM_ITERS);

    // ---- load Cs from centT (coalesced cached loads; fresh after barrier) --
    {
      float4* Cs4 = (float4*)CsBuf;
      const float4* T4 = (const float4*)g_centT;
      for (int i = t; i < (DIM * KC) / 4; i += 1024) Cs4[i] = T4[i];
    }
    const float cs0 = g_csq[ct + 0];
    const float cs1 = g_csq[ct + 1];
    const float cs2 = g_csq[ct + 2];
    const float cs3 = g_csq[ct + 3];

    // ---- assign two 64-point halves; threads t<256, P=4 x C=4 tile ----
    for (int h = 0; h < 2; ++h) {
      __syncthreads();  // protect Xs reuse (and cover Cs load on h==0)
      for (int idx = t; idx < 64 * (DIM / 4); idx += 1024) {
        const int r = idx >> 6;
        const int dq = idx & 63;
        *(float4*)&Xs[r * XPITCH + dq * 4] =
            *(const float4*)(g_R + (size_t)(p0 + h * 64 + r) * DIM + dq * 4);
      }
      __syncthreads();

      if (t < 256) {
        // exact round-4 fmaf chains (d ascending, same nesting per (p,k))
        float acc[4][4];
#pragma unroll
        for (int r = 0; r < 4; ++r)
#pragma unroll
          for (int j = 0; j < 4; ++j) acc[r][j] = 0.f;

#pragma unroll 4
        for (int d = 0; d < DIM; d += 4) {
          const float4 cv0 = *(const float4*)&CsBuf[(d + 0) * 64 + ct];
          const float4 cv1 = *(const float4*)&CsBuf[(d + 1) * 64 + ct];
          const float4 cv2 = *(const float4*)&CsBuf[(d + 2) * 64 + ct];
          const float4 cv3 = *(const float4*)&CsBuf[(d + 3) * 64 + ct];
#pragma unroll
          for (int r = 0; r < 4; ++r) {
            const float4 x = *(const float4*)&Xs[(ptg * 4 + r) * XPITCH + d];
            acc[r][0] = fmaf(x.x, cv0.x, fmaf(x.y, cv1.x, fmaf(x.z, cv2.x, fmaf(x.w, cv3.x, acc[r][0]))));
            acc[r][1] = fmaf(x.x, cv0.y, fmaf(x.y, cv1.y, fmaf(x.z, cv2.y, fmaf(x.w, cv3.y, acc[r][1]))));
            acc[r][2] = fmaf(x.x, cv0.z, fmaf(x.y, cv1.z, fmaf(x.z, cv2.z, fmaf(x.w, cv3.z, acc[r][2]))));
            acc[r][3] = fmaf(x.x, cv0.w, fmaf(x.y, cv1.w, fmaf(x.z, cv2.w, fmaf(x.w, cv3.w, acc[r][3]))));
          }
        }

#pragma unroll
        for (int r = 0; r < 4; ++r) {
          const int pl = h * 64 + ptg * 4 + r;
          const float xs = g_xsq[p0 + pl];
          float best = 3.4e38f;
          int bk = 0;
          {
            float v;
            v = (xs - 2.0f * acc[r][0]) + cs0; if (v < best) { best = v; bk = ct + 0; }
            v = (xs - 2.0f * acc[r][1]) + cs1; if (v < best) { best = v; bk = ct + 1; }
            v = (xs - 2.0f * acc[r][2]) + cs2; if (v < best) { best = v; bk = ct + 2; }
            v = (xs - 2.0f * acc[r][3]) + cs3; if (v < best) { best = v; bk = ct + 3; }
          }
          // same 16-lane butterfly (lanes = ctg within wave), same inputs
#pragma unroll
          for (int o = 1; o < 16; o <<= 1) {
            const float ov = __shfl_xor(best, o);
            const int obk = __shfl_xor(bk, o);
            if (ov < best || (ov == best && obk < bk)) { best = ov; bk = obk; }
          }
          if (ctg == 0) g_idx[p0 + pl] = bk;   // publish every iteration
        }
      }
    }
    if (final_pass) break;
    grid_barrier(c, base + (++bar));  // A: all assignments visible

    // ---- cent phase: block c computes centroid c (exact chunked chains) ----
    {
      // load all 8192 assignments into LDS (overlay on Xs)
      int* idxa = (int*)Xs;
      {
        int4* dst = (int4*)idxa;
        const int4* src = (const int4*)g_idx;
        for (int i = t; i < NPTS / 4; i += 1024) dst[i] = src[i];
      }
      __syncthreads();

      // thread (ch, dq): chunk ch's partial for cluster c, dims dq*16..+15,
      // ascending p within chunk — identical chain to the old upA.
      const int ch = t >> 4;
      const int dq = t & 15;
      float4 s[4];
#pragma unroll
      for (int q = 0; q < 4; ++q) s[q] = make_float4(0.f, 0.f, 0.f, 0.f);
      int cnt = 0;
      const int pb = ch * 128;
      for (int j4 = 0; j4 < 32; ++j4) {
        const int4 iv = *(const int4*)&idxa[pb + j4 * 4];
        // ascending j within the quad — identical order/conditions
        if (iv.x == c) {
          const float4* row = (const float4*)(g_R + (size_t)(pb + j4 * 4 + 0) * DIM) + dq * 4;
#pragma unroll
          for (int q = 0; q < 4; ++q) { const float4 x = row[q]; s[q].x += x.x; s[q].y += x.y; s[q].z += x.z; s[q].w += x.w; }
          ++cnt;
        }
        if (iv.y == c) {
          const float4* row = (const float4*)(g_R + (size_t)(pb + j4 * 4 + 1) * DIM) + dq * 4;
#pragma unroll
          for (int q = 0; q < 4; ++q) { const float4 x = row[q]; s[q].x += x.x; s[q].y += x.y; s[q].z += x.z; s[q].w += x.w; }
          ++cnt;
        }
        if (iv.z == c) {
          const float4* row = (const float4*)(g_R + (size_t)(pb + j4 * 4 + 2) * DIM) + dq * 4;
#pragma unroll
          for (int q = 0; q < 4; ++q) { const float4 x = row[q]; s[q].x += x.x; s[q].y += x.y; s[q].z += x.z; s[q].w += x.w; }
          ++cnt;
        }
        if (iv.w == c) {
          const float4* row = (const float4*)(g_R + (size_t)(pb + j4 * 4 + 3) * DIM) + dq * 4;
#pragma unroll
          for (int q = 0; q < 4; ++q) { const float4 x = row[q]; s[q].x += x.x; s[q].y += x.y; s[q].z += x.z; s[q].w += x.w; }
          ++cnt;
        }
      }
      // stage partials in LDS (CsBuf free since assign ended at barrier A)
      float* part = CsBuf;  // layout part[ch*PPITCH + d]
#pragma unroll
      for (int q = 0; q < 4; ++q)
        *(float4*)&part[ch * PPITCH + dq * 16 + q * 4] = s[q];
      if (dq == 0) cnt_s[ch] = cnt;
      __syncthreads();

      // combine in exact ascending chunk order (old upB chain), divide, csq
      if (t < 256) {
        float ssum = 0.f;
#pragma unroll 4
        for (int c2 = 0; c2 < NCHUNK; ++c2) ssum += part[c2 * PPITCH + t];
        int ctot = 0;
#pragma unroll 4
        for (int c2 = 0; c2 < NCHUNK; ++c2) ctot += cnt_s[c2];
        const float nc = (ctot > 0) ? (ssum / (float)ctot) : myc;
        myc = nc;
        g_centT[t * KC + c] = nc;
        red[t] = nc * nc;
      }
      __syncthreads();
      for (int o = 128; o > 0; o >>= 1) {
        if (t < o) red[t] += red[t + o];
        __syncthreads();
      }
      if (t == 0) g_csq[c] = red[0];
    }
    grid_barrier(c, base + (++bar));  // B: new centroids visible
  }
}

// mask write: out[b,h,i,j] = (cid[b,i]==cid[b,j]) ? 0 : -10000. 16 rows/block.
__global__ void __launch_bounds__(256) k_mask(float* __restrict__ out, int H) {
  const int blk = blockIdx.x;
  const int tiles = LSEQ / 16;  // 256
  const int b = blk / (H * tiles);
  const int h = (blk / tiles) % H;
  const int tile = blk % tiles;
  const int t = threadIdx.x;
  __shared__ int cid[LSEQ];  // 16 KB
  for (int j = t; j < LSEQ; j += 256) cid[j] = g_idx[b * LSEQ + j];
  __syncthreads();
  const size_t base = ((size_t)(b * H + h) * LSEQ + (size_t)tile * 16) * LSEQ;
  for (int r = 0; r < 16; ++r) {
    const int my = cid[tile * 16 + r];
    float4* orow = (float4*)(out + base + (size_t)r * LSEQ);
#pragma unroll
    for (int s = 0; s < 4; ++s) {
      const int c4 = s * 256 + t;
      const int j = c4 * 4;
      float4 v;
      v.x = (cid[j + 0] == my) ? 0.f : -10000.f;
      v.y = (cid[j + 1] == my) ? 0.f : -10000.f;
      v.z = (cid[j + 2] == my) ? 0.f : -10000.f;
      v.w = (cid[j + 3] == my) ? 0.f : -10000.f;
      orow[c4] = v;
    }
  }
}

// ---------------- launch -----------------------------------------------------
extern "C" void kernel_launch(void* const* d_in, const int* in_sizes, int n_in,
                              void* d_out, int out_size, void* d_ws, size_t ws_size,
                              hipStream_t stream) {
  const float* qk = (const float*)d_in[0];
  const float* W = (const float*)d_in[1];
  const int H = out_size / (NB * LSEQ * LSEQ);  // 8

  const InitIdx ii = compute_init_indices();  // pure host integer math

  k_R_xsq<<<NB * (LSEQ / 8), 256, 0, stream>>>(qk, W);
  k_kmeans<<<NBLK, 1024, 0, stream>>>(ii);
  k_mask<<<NB * H * (LSEQ / 16), 256, 0, stream>>>((float*)d_out, H);
}

// Round 15
// 599.543 us; speedup vs baseline: 1.2620x; 1.1931x over previous
//
#include <hip/hip_runtime.h>
#include <stdint.h>
#include <stddef.h>
#include <vector>
#include <algorithm>
#include <utility>

// Problem constants (B=2, L=4096, D=256, H=8, K=sqrt(L)=64, 10 Lloyd iters)
#define NPTS 8192
#define DIM  256
#define KC   64
#define LSEQ 4096
#define NB   2
#define KM_ITERS 10
#define NCHUNK 64     // global summation chunks of 128 points (bit-exact structure)
#define NBLK 128      // persistent blocks: block b owns points [b*64, b*64+64)
#define NCENT 64      // blocks 0..63 also own cluster c for the cent phase
#define XPITCH 260    // padded LDS row for X tile (1040 B, 16B-aligned rows)
#define PPITCH 257    // padded LDS row for chunk-partials

// JAX threefry mode: 1 = partitionable (default since jax 0.4.36), 0 = original
#define JAX_THREEFRY_PARTITIONABLE 1

// ---------------- static device scratch (fully rewritten every call) --------
__device__ float g_R[NPTS * DIM];          // 8 MB   rotated points (read-only in kmeans)
__device__ float g_xsq[NPTS];              // 32 KB  per-point squared norm
__device__ float g_centT[DIM * KC];        // 64 KB  centroids transposed [d][k]
__device__ float g_csq[KC];                // per-centroid squared norm
__device__ int   g_idx[NPTS];              // assignments (every iter; final = cid)

// Barrier state (monotone across graph replays; each block reads its own
// arrival flag at entry as base — deterministic per replay). Per-block padded
// arrival + release lines (one poller per line).
__device__ unsigned g_arrive[NBLK * 16];       // block c arrives on g_arrive[c*16]
__device__ unsigned g_release_arr[NBLK * 16];  // block c polls g_release_arr[c*16]

__device__ __forceinline__ void grid_barrier(int c, unsigned target) {
  __syncthreads();
  const int t = threadIdx.x;
  if (t == 0) {
    // release: publishes this block's prior writes (one L2 wb)
    __hip_atomic_store(&g_arrive[c * 16], target, __ATOMIC_RELEASE,
                       __HIP_MEMORY_SCOPE_AGENT);
  }
  if (c == 0) {
    // leader: threads t<NBLK poll the arrival lines in parallel (1/line)
    if (t < NBLK) {
      while (__hip_atomic_load(&g_arrive[t * 16], __ATOMIC_RELAXED,
                               __HIP_MEMORY_SCOPE_AGENT) < target) {
        __builtin_amdgcn_s_sleep(1);
      }
    }
    __syncthreads();
    if (t < NBLK) {
      if (t == 0) {
        __builtin_amdgcn_fence(__ATOMIC_ACQUIRE, "agent");  // pairs w/ arrivals
        __builtin_amdgcn_fence(__ATOMIC_RELEASE, "agent");  // before fanout
      }
      __hip_atomic_store(&g_release_arr[t * 16], target, __ATOMIC_RELAXED,
                         __HIP_MEMORY_SCOPE_AGENT);
    }
  } else {
    if (t == 0) {
      while (__hip_atomic_load(&g_release_arr[c * 16], __ATOMIC_RELAXED,
                               __HIP_MEMORY_SCOPE_AGENT) < target) {
        __builtin_amdgcn_s_sleep(1);
      }
      __builtin_amdgcn_fence(__ATOMIC_ACQUIRE, "agent");  // transitive pairing
    }
  }
  __syncthreads();
}

// ---------------- host threefry2x32 (exact JAX semantics) -------------------
static inline uint32_t rotl32(uint32_t x, int r) { return (x << r) | (x >> (32 - r)); }

static void threefry2x32(uint32_t k0, uint32_t k1, uint32_t x0, uint32_t x1,
                         uint32_t& o0, uint32_t& o1) {
  const uint32_t ks0 = k0, ks1 = k1, ks2 = k0 ^ k1 ^ 0x1BD11BDAu;
  const int r1[4] = {13, 15, 26, 6}, r2[4] = {17, 29, 16, 24};
  x0 += ks0; x1 += ks1;
  for (int i = 0; i < 4; ++i) { x0 += x1; x1 = rotl32(x1, r1[i]); x1 ^= x0; }
  x0 += ks1; x1 += ks2 + 1u;
  for (int i = 0; i < 4; ++i) { x0 += x1; x1 = rotl32(x1, r2[i]); x1 ^= x0; }
  x0 += ks2; x1 += ks0 + 2u;
  for (int i = 0; i < 4; ++i) { x0 += x1; x1 = rotl32(x1, r1[i]); x1 ^= x0; }
  x0 += ks0; x1 += ks1 + 3u;
  for (int i = 0; i < 4; ++i) { x0 += x1; x1 = rotl32(x1, r2[i]); x1 ^= x0; }
  x0 += ks1; x1 += ks2 + 4u;
  for (int i = 0; i < 4; ++i) { x0 += x1; x1 = rotl32(x1, r1[i]); x1 ^= x0; }
  x0 += ks2; x1 += ks0 + 5u;
  o0 = x0; o1 = x1;
}

struct InitIdx { int v[KC]; };

// jax.random.choice(key(42), 8192, (64,), replace=False)
//  = permutation(key, arange(8192))[:64]  (2-round threefry shuffle)
static InitIdx compute_init_indices() {
  uint32_t k0 = 0u, k1 = 42u;  // jax.random.key(42) -> [0, 42]
  std::vector<int> val(NPTS);
  for (int i = 0; i < NPTS; ++i) val[i] = i;
  std::vector<std::pair<uint32_t, int>> kv(NPTS);
  for (int round = 0; round < 2; ++round) {
    uint32_t nk0, nk1, sk0, sk1;
#if JAX_THREEFRY_PARTITIONABLE
    threefry2x32(k0, k1, 0u, 0u, nk0, nk1);
    threefry2x32(k0, k1, 0u, 1u, sk0, sk1);
    k0 = nk0; k1 = nk1;
    for (int i = 0; i < NPTS; ++i) {
      uint32_t o0, o1;
      threefry2x32(sk0, sk1, 0u, (uint32_t)i, o0, o1);
      kv[i] = std::make_pair(o0 ^ o1, val[i]);
    }
#else
    uint32_t a0, a1, b0, b1;
    threefry2x32(k0, k1, 0u, 2u, a0, a1);
    threefry2x32(k0, k1, 1u, 3u, b0, b1);
    nk0 = a0; nk1 = b0; sk0 = a1; sk1 = b1;
    k0 = nk0; k1 = nk1;
    for (int i = 0; i < NPTS / 2; ++i) {
      uint32_t o0, o1;
      threefry2x32(sk0, sk1, (uint32_t)i, (uint32_t)(i + NPTS / 2), o0, o1);
      kv[i] = std::make_pair(o0, 0);
      kv[i + NPTS / 2] = std::make_pair(o1, 0);
    }
    for (int i = 0; i < NPTS; ++i) kv[i].second = val[i];
#endif
    std::stable_sort(kv.begin(), kv.end(),
                     [](const std::pair<uint32_t, int>& a,
                        const std::pair<uint32_t, int>& b) { return a.first < b.first; });
    for (int i = 0; i < NPTS; ++i) val[i] = kv[i].second;
  }
  InitIdx ii;
  for (int k = 0; k < KC; ++k) ii.v[k] = val[k];
  return ii;
}

// ---------------- kernels ---------------------------------------------------

// Fused R-GEMM + xsq (unchanged).
__global__ void __launch_bounds__(256) k_R_xsq(const float* __restrict__ qk,
                                               const float* __restrict__ W) {
  __shared__ float q[8][DIM];
  const int blk = blockIdx.x;               // 0..1023
  const int b = blk / (LSEQ / 8);
  const int r0 = (blk % (LSEQ / 8)) * 8;
  const int t = threadIdx.x;
  for (int r = 0; r < 8; ++r)
    q[r][t] = qk[((size_t)b * LSEQ + r0 + r) * DIM + t];
  __syncthreads();
  float acc[8] = {0.f, 0.f, 0.f, 0.f, 0.f, 0.f, 0.f, 0.f};
  const float* Wb = W + (size_t)b * DIM * DIM;
  for (int d = 0; d < DIM; ++d) {
    const float w = Wb[d * DIM + t];
#pragma unroll
    for (int r = 0; r < 8; ++r) acc[r] = fmaf(q[r][d], w, acc[r]);
  }
  for (int r = 0; r < 8; ++r)
    g_R[((size_t)b * LSEQ + r0 + r) * DIM + t] = acc[r];
  __syncthreads();
  for (int r = 0; r < 8; ++r) q[r][t] = acc[r];
  __syncthreads();
  const int w = t >> 6, lane = t & 63;
#pragma unroll
  for (int rr = 0; rr < 2; ++rr) {
    const int r = w * 2 + rr;
    const float4 x = *(const float4*)&q[r][lane * 4];
    float s = x.x * x.x + x.y * x.y + x.z * x.z + x.w * x.w;
    for (int o = 32; o > 0; o >>= 1) s += __shfl_xor(s, o);
    if (lane == 0) g_xsq[(size_t)b * LSEQ + r0 + r] = s;
  }
}

// Persistent k-means, 128 blocks x 1024 threads. Block b owns 64 points
// (= one round-13 half): assign is the VERBATIM round-4/13 P4C4 tile on the
// same Xs/Cs values -> bit-identical distances/decisions. Cent phase runs on
// blocks 0..63 only (verbatim round-13 code; chunk ids are global).
__global__ void __launch_bounds__(1024) k_kmeans(InitIdx ii) {
  __shared__ __align__(16) float CsBuf[NCHUNK * PPITCH];  // Cs[d*64+k] in assign; partials in cent
  __shared__ __align__(16) float Xs[64 * XPITCH];         // 64-row X tile; aliased as idx_all in cent
  __shared__ float red[256];
  __shared__ int cnt_s[NCHUNK];
  __shared__ unsigned base_s;
  const int t = threadIdx.x;          // 0..1023
  const int c = blockIdx.x;           // 0..127; owns points [c*64, c*64+64)
  const int p0 = c * 64;
  const int ptg = t >> 4;             // for t<256: 4-point group 0..15
  const int ctg = t & 15;             // 4-cluster group 0..15
  const int ct = ctg * 4;

  if (t == 0)
    base_s = __hip_atomic_load(&g_arrive[c * 16], __ATOMIC_RELAXED,
                               __HIP_MEMORY_SCOPE_AGENT);
  __syncthreads();
  const unsigned base = base_s;
  unsigned bar = 0;

  // ---- init centroid k=c for c<64 (exact chain, threads 0..255) ----
  float myc = 0.f;
  if (c < NCENT) {
    if (t < 256) {
      const float cv = g_R[(size_t)ii.v[c] * DIM + t];
      myc = cv;
      g_centT[t * KC + c] = cv;
      red[t] = cv * cv;
    }
    __syncthreads();
    for (int o = 128; o > 0; o >>= 1) {
      if (t < o) red[t] += red[t + o];
      __syncthreads();
    }
    if (t == 0) g_csq[c] = red[0];
  }
  grid_barrier(c, base + (++bar));

  for (int it = 0; it <= KM_ITERS; ++it) {
    const bool final_pass = (it == KM_ITERS);

    // ---- load Cs from centT (coalesced cached loads; fresh after barrier) --
    {
      float4* Cs4 = (float4*)CsBuf;
      const float4* T4 = (const float4*)g_centT;
      for (int i = t; i < (DIM * KC) / 4; i += 1024) Cs4[i] = T4[i];
    }
    const float cs0 = g_csq[ct + 0];
    const float cs1 = g_csq[ct + 1];
    const float cs2 = g_csq[ct + 2];
    const float cs3 = g_csq[ct + 3];

    // ---- stage this block's 64 X rows (one pass; no halves) ----
    __syncthreads();  // protect Xs reuse from previous phase
    for (int idx = t; idx < 64 * (DIM / 4); idx += 1024) {
      const int r = idx >> 6;
      const int dq = idx & 63;
      *(float4*)&Xs[r * XPITCH + dq * 4] =
          *(const float4*)(g_R + (size_t)(p0 + r) * DIM + dq * 4);
    }
    __syncthreads();

    // ---- assign 64 points; threads t<256, P=4 x C=4 tile (verbatim) ----
    if (t < 256) {
      float acc[4][4];
#pragma unroll
      for (int r = 0; r < 4; ++r)
#pragma unroll
        for (int j = 0; j < 4; ++j) acc[r][j] = 0.f;

#pragma unroll 4
      for (int d = 0; d < DIM; d += 4) {
        const float4 cv0 = *(const float4*)&CsBuf[(d + 0) * 64 + ct];
        const float4 cv1 = *(const float4*)&CsBuf[(d + 1) * 64 + ct];
        const float4 cv2 = *(const float4*)&CsBuf[(d + 2) * 64 + ct];
        const float4 cv3 = *(const float4*)&CsBuf[(d + 3) * 64 + ct];
#pragma unroll
        for (int r = 0; r < 4; ++r) {
          const float4 x = *(const float4*)&Xs[(ptg * 4 + r) * XPITCH + d];
          acc[r][0] = fmaf(x.x, cv0.x, fmaf(x.y, cv1.x, fmaf(x.z, cv2.x, fmaf(x.w, cv3.x, acc[r][0]))));
          acc[r][1] = fmaf(x.x, cv0.y, fmaf(x.y, cv1.y, fmaf(x.z, cv2.y, fmaf(x.w, cv3.y, acc[r][1]))));
          acc[r][2] = fmaf(x.x, cv0.z, fmaf(x.y, cv1.z, fmaf(x.z, cv2.z, fmaf(x.w, cv3.z, acc[r][2]))));
          acc[r][3] = fmaf(x.x, cv0.w, fmaf(x.y, cv1.w, fmaf(x.z, cv2.w, fmaf(x.w, cv3.w, acc[r][3]))));
        }
      }

#pragma unroll
      for (int r = 0; r < 4; ++r) {
        const int pl = ptg * 4 + r;
        const float xs = g_xsq[p0 + pl];
        float best = 3.4e38f;
        int bk = 0;
        {
          float v;
          v = (xs - 2.0f * acc[r][0]) + cs0; if (v < best) { best = v; bk = ct + 0; }
          v = (xs - 2.0f * acc[r][1]) + cs1; if (v < best) { best = v; bk = ct + 1; }
          v = (xs - 2.0f * acc[r][2]) + cs2; if (v < best) { best = v; bk = ct + 2; }
          v = (xs - 2.0f * acc[r][3]) + cs3; if (v < best) { best = v; bk = ct + 3; }
        }
        // same 16-lane butterfly (lanes = ctg within wave), same inputs
#pragma unroll
        for (int o = 1; o < 16; o <<= 1) {
          const float ov = __shfl_xor(best, o);
          const int obk = __shfl_xor(bk, o);
          if (ov < best || (ov == best && obk < bk)) { best = ov; bk = obk; }
        }
        if (ctg == 0) g_idx[p0 + pl] = bk;   // publish every iteration
      }
    }
    if (final_pass) break;
    grid_barrier(c, base + (++bar));  // A: all assignments visible

    // ---- cent phase: blocks 0..63 compute centroid c (verbatim r13) ----
    if (c < NCENT) {
      // load all 8192 assignments into LDS (overlay on Xs)
      int* idxa = (int*)Xs;
      {
        int4* dst = (int4*)idxa;
        const int4* src = (const int4*)g_idx;
        for (int i = t; i < NPTS / 4; i += 1024) dst[i] = src[i];
      }
      __syncthreads();

      // thread (ch, dq): chunk ch's partial for cluster c, dims dq*16..+15,
      // ascending p within chunk — identical chain to the old upA.
      const int ch = t >> 4;
      const int dq = t & 15;
      float4 s[4];
#pragma unroll
      for (int q = 0; q < 4; ++q) s[q] = make_float4(0.f, 0.f, 0.f, 0.f);
      int cnt = 0;
      const int pb = ch * 128;
      for (int j4 = 0; j4 < 32; ++j4) {
        const int4 iv = *(const int4*)&idxa[pb + j4 * 4];
        // ascending j within the quad — identical order/conditions
        if (iv.x == c) {
          const float4* row = (const float4*)(g_R + (size_t)(pb + j4 * 4 + 0) * DIM) + dq * 4;
#pragma unroll
          for (int q = 0; q < 4; ++q) { const float4 x = row[q]; s[q].x += x.x; s[q].y += x.y; s[q].z += x.z; s[q].w += x.w; }
          ++cnt;
        }
        if (iv.y == c) {
          const float4* row = (const float4*)(g_R + (size_t)(pb + j4 * 4 + 1) * DIM) + dq * 4;
#pragma unroll
          for (int q = 0; q < 4; ++q) { const float4 x = row[q]; s[q].x += x.x; s[q].y += x.y; s[q].z += x.z; s[q].w += x.w; }
          ++cnt;
        }
        if (iv.z == c) {
          const float4* row = (const float4*)(g_R + (size_t)(pb + j4 * 4 + 2) * DIM) + dq * 4;
#pragma unroll
          for (int q = 0; q < 4; ++q) { const float4 x = row[q]; s[q].x += x.x; s[q].y += x.y; s[q].z += x.z; s[q].w += x.w; }
          ++cnt;
        }
        if (iv.w == c) {
          const float4* row = (const float4*)(g_R + (size_t)(pb + j4 * 4 + 3) * DIM) + dq * 4;
#pragma unroll
          for (int q = 0; q < 4; ++q) { const float4 x = row[q]; s[q].x += x.x; s[q].y += x.y; s[q].z += x.z; s[q].w += x.w; }
          ++cnt;
        }
      }
      // stage partials in LDS (CsBuf free since assign ended at barrier A)
      float* part = CsBuf;  // layout part[ch*PPITCH + d]
#pragma unroll
      for (int q = 0; q < 4; ++q)
        *(float4*)&part[ch * PPITCH + dq * 16 + q * 4] = s[q];
      if (dq == 0) cnt_s[ch] = cnt;
      __syncthreads();

      // combine in exact ascending chunk order (old upB chain), divide, csq
      if (t < 256) {
        float ssum = 0.f;
#pragma unroll 4
        for (int c2 = 0; c2 < NCHUNK; ++c2) ssum += part[c2 * PPITCH + t];
        int ctot = 0;
#pragma unroll 4
        for (int c2 = 0; c2 < NCHUNK; ++c2) ctot += cnt_s[c2];
        const float nc = (ctot > 0) ? (ssum / (float)ctot) : myc;
        myc = nc;
        g_centT[t * KC + c] = nc;
        red[t] = nc * nc;
      }
      __syncthreads();
      for (int o = 128; o > 0; o >>= 1) {
        if (t < o) red[t] += red[t + o];
        __syncthreads();
      }
      if (t == 0) g_csq[c] = red[0];
    }
    grid_barrier(c, base + (++bar));  // B: new centroids visible
  }
}

// mask write: out[b,h,i,j] = (cid[b,i]==cid[b,j]) ? 0 : -10000. 16 rows/block.
__global__ void __launch_bounds__(256) k_mask(float* __restrict__ out, int H) {
  const int blk = blockIdx.x;
  const int tiles = LSEQ / 16;  // 256
  const int b = blk / (H * tiles);
  const int h = (blk / tiles) % H;
  const int tile = blk % tiles;
  const int t = threadIdx.x;
  __shared__ int cid[LSEQ];  // 16 KB
  for (int j = t; j < LSEQ; j += 256) cid[j] = g_idx[b * LSEQ + j];
  __syncthreads();
  const size_t base = ((size_t)(b * H + h) * LSEQ + (size_t)tile * 16) * LSEQ;
  for (int r = 0; r < 16; ++r) {
    const int my = cid[tile * 16 + r];
    float4* orow = (float4*)(out + base + (size_t)r * LSEQ);
#pragma unroll
    for (int s = 0; s < 4; ++s) {
      const int c4 = s * 256 + t;
      const int j = c4 * 4;
      float4 v;
      v.x = (cid[j + 0] == my) ? 0.f : -10000.f;
      v.y = (cid[j + 1] == my) ? 0.f : -10000.f;
      v.z = (cid[j + 2] == my) ? 0.f : -10000.f;
      v.w = (cid[j + 3] == my) ? 0.f : -10000.f;
      orow[c4] = v;
    }
  }
}

// ---------------- launch -----------------------------------------------------
extern "C" void kernel_launch(void* const* d_in, const int* in_sizes, int n_in,
                              void* d_out, int out_size, void* d_ws, size_t ws_size,
                              hipStream_t stream) {
  const float* qk = (const float*)d_in[0];
  const float* W = (const float*)d_in[1];
  const int H = out_size / (NB * LSEQ * LSEQ);  // 8

  const InitIdx ii = compute_init_indices();  // pure host integer math

  k_R_xsq<<<NB * (LSEQ / 8), 256, 0, stream>>>(qk, W);
  k_kmeans<<<NBLK, 1024, 0, stream>>>(ii);
  k_mask<<<NB * H * (LSEQ / 16), 256, 0, stream>>>((float*)d_out, H);
}

// Round 16
// 597.017 us; speedup vs baseline: 1.2673x; 1.0042x over previous
//
#include <hip/hip_runtime.h>
#include <stdint.h>
#include <stddef.h>
#include <vector>
#include <algorithm>
#include <utility>

// Problem constants (B=2, L=4096, D=256, H=8, K=sqrt(L)=64, 10 Lloyd iters)
#define NPTS 8192
#define DIM  256
#define KC   64
#define LSEQ 4096
#define NB   2
#define KM_ITERS 10
#define NCHUNK 64     // global summation chunks of 128 points (bit-exact structure)
#define NBLK 128      // persistent blocks: block b owns points [b*64, b*64+64)
#define NCENT 64      // blocks 0..63 also own cluster c for the cent phase
#define XPITCH 260    // padded LDS row for X tile (1040 B, 16B-aligned rows)
#define PPITCH 257    // padded LDS row for chunk-partials

// JAX threefry mode: 1 = partitionable (default since jax 0.4.36), 0 = original
#define JAX_THREEFRY_PARTITIONABLE 1

// ---------------- static device scratch (fully rewritten every call) --------
__device__ float g_R[NPTS * DIM];          // 8 MB   rotated points (read-only in kmeans)
__device__ float g_xsq[NPTS];              // 32 KB  per-point squared norm
__device__ float g_centT[DIM * KC];        // 64 KB  centroids transposed [d][k]
__device__ float g_csq[KC];                // per-centroid squared norm
__device__ int   g_idx[NPTS];              // assignments (every iter; final = cid)

// Barrier state (monotone across graph replays; each block reads its own
// arrival flag at entry as base — deterministic per replay). Per-block padded
// arrival + release lines (one poller per line).
__device__ unsigned g_arrive[NBLK * 16];       // block c arrives on g_arrive[c*16]
__device__ unsigned g_release_arr[NBLK * 16];  // block c polls g_release_arr[c*16]

__device__ __forceinline__ void grid_barrier(int c, unsigned target) {
  __syncthreads();
  const int t = threadIdx.x;
  if (t == 0) {
    // release: publishes this block's prior writes (one L2 wb)
    __hip_atomic_store(&g_arrive[c * 16], target, __ATOMIC_RELEASE,
                       __HIP_MEMORY_SCOPE_AGENT);
  }
  if (c == 0) {
    // leader: threads t<NBLK poll the arrival lines in parallel (1/line)
    if (t < NBLK) {
      while (__hip_atomic_load(&g_arrive[t * 16], __ATOMIC_RELAXED,
                               __HIP_MEMORY_SCOPE_AGENT) < target) {
        __builtin_amdgcn_s_sleep(1);
      }
    }
    __syncthreads();
    if (t < NBLK) {
      if (t == 0) {
        __builtin_amdgcn_fence(__ATOMIC_ACQUIRE, "agent");  // pairs w/ arrivals
        __builtin_amdgcn_fence(__ATOMIC_RELEASE, "agent");  // before fanout
      }
      __hip_atomic_store(&g_release_arr[t * 16], target, __ATOMIC_RELAXED,
                         __HIP_MEMORY_SCOPE_AGENT);
    }
  } else {
    if (t == 0) {
      while (__hip_atomic_load(&g_release_arr[c * 16], __ATOMIC_RELAXED,
                               __HIP_MEMORY_SCOPE_AGENT) < target) {
        __builtin_amdgcn_s_sleep(1);
      }
      __builtin_amdgcn_fence(__ATOMIC_ACQUIRE, "agent");  // transitive pairing
    }
  }
  __syncthreads();
}

// ---------------- host threefry2x32 (exact JAX semantics) -------------------
static inline uint32_t rotl32(uint32_t x, int r) { return (x << r) | (x >> (32 - r)); }

static void threefry2x32(uint32_t k0, uint32_t k1, uint32_t x0, uint32_t x1,
                         uint32_t& o0, uint32_t& o1) {
  const uint32_t ks0 = k0, ks1 = k1, ks2 = k0 ^ k1 ^ 0x1BD11BDAu;
  const int r1[4] = {13, 15, 26, 6}, r2[4] = {17, 29, 16, 24};
  x0 += ks0; x1 += ks1;
  for (int i = 0; i < 4; ++i) { x0 += x1; x1 = rotl32(x1, r1[i]); x1 ^= x0; }
  x0 += ks1; x1 += ks2 + 1u;
  for (int i = 0; i < 4; ++i) { x0 += x1; x1 = rotl32(x1, r2[i]); x1 ^= x0; }
  x0 += ks2; x1 += ks0 + 2u;
  for (int i = 0; i < 4; ++i) { x0 += x1; x1 = rotl32(x1, r1[i]); x1 ^= x0; }
  x0 += ks0; x1 += ks1 + 3u;
  for (int i = 0; i < 4; ++i) { x0 += x1; x1 = rotl32(x1, r2[i]); x1 ^= x0; }
  x0 += ks1; x1 += ks2 + 4u;
  for (int i = 0; i < 4; ++i) { x0 += x1; x1 = rotl32(x1, r1[i]); x1 ^= x0; }
  x0 += ks2; x1 += ks0 + 5u;
  o0 = x0; o1 = x1;
}

struct InitIdx { int v[KC]; };

// jax.random.choice(key(42), 8192, (64,), replace=False)
//  = permutation(key, arange(8192))[:64]  (2-round threefry shuffle)
static InitIdx compute_init_indices() {
  uint32_t k0 = 0u, k1 = 42u;  // jax.random.key(42) -> [0, 42]
  std::vector<int> val(NPTS);
  for (int i = 0; i < NPTS; ++i) val[i] = i;
  std::vector<std::pair<uint32_t, int>> kv(NPTS);
  for (int round = 0; round < 2; ++round) {
    uint32_t nk0, nk1, sk0, sk1;
#if JAX_THREEFRY_PARTITIONABLE
    threefry2x32(k0, k1, 0u, 0u, nk0, nk1);
    threefry2x32(k0, k1, 0u, 1u, sk0, sk1);
    k0 = nk0; k1 = nk1;
    for (int i = 0; i < NPTS; ++i) {
      uint32_t o0, o1;
      threefry2x32(sk0, sk1, 0u, (uint32_t)i, o0, o1);
      kv[i] = std::make_pair(o0 ^ o1, val[i]);
    }
#else
    uint32_t a0, a1, b0, b1;
    threefry2x32(k0, k1, 0u, 2u, a0, a1);
    threefry2x32(k0, k1, 1u, 3u, b0, b1);
    nk0 = a0; nk1 = b0; sk0 = a1; sk1 = b1;
    k0 = nk0; k1 = nk1;
    for (int i = 0; i < NPTS / 2; ++i) {
      uint32_t o0, o1;
      threefry2x32(sk0, sk1, (uint32_t)i, (uint32_t)(i + NPTS / 2), o0, o1);
      kv[i] = std::make_pair(o0, 0);
      kv[i + NPTS / 2] = std::make_pair(o1, 0);
    }
    for (int i = 0; i < NPTS; ++i) kv[i].second = val[i];
#endif
    std::stable_sort(kv.begin(), kv.end(),
                     [](const std::pair<uint32_t, int>& a,
                        const std::pair<uint32_t, int>& b) { return a.first < b.first; });
    for (int i = 0; i < NPTS; ++i) val[i] = kv[i].second;
  }
  InitIdx ii;
  for (int k = 0; k < KC; ++k) ii.v[k] = val[k];
  return ii;
}

// ---------------- kernels ---------------------------------------------------

// Fused R-GEMM + xsq (unchanged).
__global__ void __launch_bounds__(256) k_R_xsq(const float* __restrict__ qk,
                                               const float* __restrict__ W) {
  __shared__ float q[8][DIM];
  const int blk = blockIdx.x;               // 0..1023
  const int b = blk / (LSEQ / 8);
  const int r0 = (blk % (LSEQ / 8)) * 8;
  const int t = threadIdx.x;
  for (int r = 0; r < 8; ++r)
    q[r][t] = qk[((size_t)b * LSEQ + r0 + r) * DIM + t];
  __syncthreads();
  float acc[8] = {0.f, 0.f, 0.f, 0.f, 0.f, 0.f, 0.f, 0.f};
  const float* Wb = W + (size_t)b * DIM * DIM;
  for (int d = 0; d < DIM; ++d) {
    const float w = Wb[d * DIM + t];
#pragma unroll
    for (int r = 0; r < 8; ++r) acc[r] = fmaf(q[r][d], w, acc[r]);
  }
  for (int r = 0; r < 8; ++r)
    g_R[((size_t)b * LSEQ + r0 + r) * DIM + t] = acc[r];
  __syncthreads();
  for (int r = 0; r < 8; ++r) q[r][t] = acc[r];
  __syncthreads();
  const int w = t >> 6, lane = t & 63;
#pragma unroll
  for (int rr = 0; rr < 2; ++rr) {
    const int r = w * 2 + rr;
    const float4 x = *(const float4*)&q[r][lane * 4];
    float s = x.x * x.x + x.y * x.y + x.z * x.z + x.w * x.w;
    for (int o = 32; o > 0; o >>= 1) s += __shfl_xor(s, o);
    if (lane == 0) g_xsq[(size_t)b * LSEQ + r0 + r] = s;
  }
}

// Persistent k-means, 128 blocks x 1024 threads.
//  - Xs staged ONCE before the loop (each block's 64 points never change).
//  - xsq hoisted into registers.
//  - assign: 512 threads, P2C4 tile — per-(point,cluster) fmaf chains and the
//    16-lane argmin butterfly are VERBATIM (same inputs/nesting/lane groups)
//    -> bit-identical decisions.
//  - cent (blocks 0..63): idx read directly from global (L2-broadcast);
//    partials/combine/csq verbatim round-15 chains.
__global__ void __launch_bounds__(1024) k_kmeans(InitIdx ii) {
  __shared__ __align__(16) float CsBuf[NCHUNK * PPITCH];  // Cs[d*64+k] in assign; partials in cent
  __shared__ __align__(16) float Xs[64 * XPITCH];         // 64-row X tile (loaded once)
  __shared__ float red[256];
  __shared__ int cnt_s[NCHUNK];
  __shared__ unsigned base_s;
  const int t = threadIdx.x;          // 0..1023
  const int c = blockIdx.x;           // 0..127; owns points [c*64, c*64+64)
  const int p0 = c * 64;
  const int ptg = t >> 4;             // for t<512: 2-point group 0..31
  const int ctg = t & 15;             // 4-cluster group 0..15
  const int ct = ctg * 4;

  if (t == 0)
    base_s = __hip_atomic_load(&g_arrive[c * 16], __ATOMIC_RELAXED,
                               __HIP_MEMORY_SCOPE_AGENT);

  // ---- one-time: stage this block's 64 X rows + per-thread xsq ----
  for (int idx = t; idx < 64 * (DIM / 4); idx += 1024) {
    const int r = idx >> 6;
    const int dq = idx & 63;
    *(float4*)&Xs[r * XPITCH + dq * 4] =
        *(const float4*)(g_R + (size_t)(p0 + r) * DIM + dq * 4);
  }
  float xs_reg[2] = {0.f, 0.f};
  if (t < 512) {
    xs_reg[0] = g_xsq[p0 + ptg * 2 + 0];
    xs_reg[1] = g_xsq[p0 + ptg * 2 + 1];
  }
  __syncthreads();
  const unsigned base = base_s;
  unsigned bar = 0;

  // ---- init centroid k=c for c<64 (exact chain, threads 0..255) ----
  float myc = 0.f;
  if (c < NCENT) {
    if (t < 256) {
      const float cv = g_R[(size_t)ii.v[c] * DIM + t];
      myc = cv;
      g_centT[t * KC + c] = cv;
      red[t] = cv * cv;
    }
    __syncthreads();
    for (int o = 128; o > 0; o >>= 1) {
      if (t < o) red[t] += red[t + o];
      __syncthreads();
    }
    if (t == 0) g_csq[c] = red[0];
  }
  grid_barrier(c, base + (++bar));

  for (int it = 0; it <= KM_ITERS; ++it) {
    const bool final_pass = (it == KM_ITERS);

    // ---- load Cs from centT (coalesced cached loads; fresh after barrier) --
    {
      float4* Cs4 = (float4*)CsBuf;
      const float4* T4 = (const float4*)g_centT;
      for (int i = t; i < (DIM * KC) / 4; i += 1024) Cs4[i] = T4[i];
    }
    __syncthreads();

    // ---- assign 64 points; threads t<512, P=2 x C=4 tile (verbatim chains) --
    if (t < 512) {
      const float cs0 = g_csq[ct + 0];
      const float cs1 = g_csq[ct + 1];
      const float cs2 = g_csq[ct + 2];
      const float cs3 = g_csq[ct + 3];

      float acc[2][4];
#pragma unroll
      for (int r = 0; r < 2; ++r)
#pragma unroll
        for (int j = 0; j < 4; ++j) acc[r][j] = 0.f;

#pragma unroll 4
      for (int d = 0; d < DIM; d += 4) {
        const float4 cv0 = *(const float4*)&CsBuf[(d + 0) * 64 + ct];
        const float4 cv1 = *(const float4*)&CsBuf[(d + 1) * 64 + ct];
        const float4 cv2 = *(const float4*)&CsBuf[(d + 2) * 64 + ct];
        const float4 cv3 = *(const float4*)&CsBuf[(d + 3) * 64 + ct];
#pragma unroll
        for (int r = 0; r < 2; ++r) {
          const float4 x = *(const float4*)&Xs[(ptg * 2 + r) * XPITCH + d];
          acc[r][0] = fmaf(x.x, cv0.x, fmaf(x.y, cv1.x, fmaf(x.z, cv2.x, fmaf(x.w, cv3.x, acc[r][0]))));
          acc[r][1] = fmaf(x.x, cv0.y, fmaf(x.y, cv1.y, fmaf(x.z, cv2.y, fmaf(x.w, cv3.y, acc[r][1]))));
          acc[r][2] = fmaf(x.x, cv0.z, fmaf(x.y, cv1.z, fmaf(x.z, cv2.z, fmaf(x.w, cv3.z, acc[r][2]))));
          acc[r][3] = fmaf(x.x, cv0.w, fmaf(x.y, cv1.w, fmaf(x.z, cv2.w, fmaf(x.w, cv3.w, acc[r][3]))));
        }
      }

#pragma unroll
      for (int r = 0; r < 2; ++r) {
        const int pl = ptg * 2 + r;
        const float xs = xs_reg[r];
        float best = 3.4e38f;
        int bk = 0;
        {
          float v;
          v = (xs - 2.0f * acc[r][0]) + cs0; if (v < best) { best = v; bk = ct + 0; }
          v = (xs - 2.0f * acc[r][1]) + cs1; if (v < best) { best = v; bk = ct + 1; }
          v = (xs - 2.0f * acc[r][2]) + cs2; if (v < best) { best = v; bk = ct + 2; }
          v = (xs - 2.0f * acc[r][3]) + cs3; if (v < best) { best = v; bk = ct + 3; }
        }
        // same 16-lane butterfly (ctg lanes within the wave), same inputs
#pragma unroll
        for (int o = 1; o < 16; o <<= 1) {
          const float ov = __shfl_xor(best, o);
          const int obk = __shfl_xor(bk, o);
          if (ov < best || (ov == best && obk < bk)) { best = ov; bk = obk; }
        }
        if (ctg == 0) g_idx[p0 + pl] = bk;   // publish every iteration
      }
    }
    if (final_pass) break;
    grid_barrier(c, base + (++bar));  // A: all assignments visible

    // ---- cent phase: blocks 0..63 compute centroid c (verbatim chains) ----
    if (c < NCENT) {
      // thread (ch, dq): chunk ch's partial for cluster c, dims dq*16..+15,
      // ascending p within chunk — idx read straight from global (L2-hot).
      const int ch = t >> 4;
      const int dq = t & 15;
      float4 s[4];
#pragma unroll
      for (int q = 0; q < 4; ++q) s[q] = make_float4(0.f, 0.f, 0.f, 0.f);
      int cnt = 0;
      const int pb = ch * 128;
      for (int j4 = 0; j4 < 32; ++j4) {
        const int4 iv = *(const int4*)(g_idx + pb + j4 * 4);
        // ascending j within the quad — identical order/conditions
        if (iv.x == c) {
          const float4* row = (const float4*)(g_R + (size_t)(pb + j4 * 4 + 0) * DIM) + dq * 4;
#pragma unroll
          for (int q = 0; q < 4; ++q) { const float4 x = row[q]; s[q].x += x.x; s[q].y += x.y; s[q].z += x.z; s[q].w += x.w; }
          ++cnt;
        }
        if (iv.y == c) {
          const float4* row = (const float4*)(g_R + (size_t)(pb + j4 * 4 + 1) * DIM) + dq * 4;
#pragma unroll
          for (int q = 0; q < 4; ++q) { const float4 x = row[q]; s[q].x += x.x; s[q].y += x.y; s[q].z += x.z; s[q].w += x.w; }
          ++cnt;
        }
        if (iv.z == c) {
          const float4* row = (const float4*)(g_R + (size_t)(pb + j4 * 4 + 2) * DIM) + dq * 4;
#pragma unroll
          for (int q = 0; q < 4; ++q) { const float4 x = row[q]; s[q].x += x.x; s[q].y += x.y; s[q].z += x.z; s[q].w += x.w; }
          ++cnt;
        }
        if (iv.w == c) {
          const float4* row = (const float4*)(g_R + (size_t)(pb + j4 * 4 + 3) * DIM) + dq * 4;
#pragma unroll
          for (int q = 0; q < 4; ++q) { const float4 x = row[q]; s[q].x += x.x; s[q].y += x.y; s[q].z += x.z; s[q].w += x.w; }
          ++cnt;
        }
      }
      // stage partials in LDS (CsBuf free: assign's reads ended at barrier A)
      float* part = CsBuf;  // layout part[ch*PPITCH + d]
#pragma unroll
      for (int q = 0; q < 4; ++q)
        *(float4*)&part[ch * PPITCH + dq * 16 + q * 4] = s[q];
      if (dq == 0) cnt_s[ch] = cnt;
      __syncthreads();

      // combine in exact ascending chunk order (old upB chain), divide, csq
      if (t < 256) {
        float ssum = 0.f;
#pragma unroll 4
        for (int c2 = 0; c2 < NCHUNK; ++c2) ssum += part[c2 * PPITCH + t];
        int ctot = 0;
#pragma unroll 4
        for (int c2 = 0; c2 < NCHUNK; ++c2) ctot += cnt_s[c2];
        const float nc = (ctot > 0) ? (ssum / (float)ctot) : myc;
        myc = nc;
        g_centT[t * KC + c] = nc;
        red[t] = nc * nc;
      }
      __syncthreads();
      for (int o = 128; o > 0; o >>= 1) {
        if (t < o) red[t] += red[t + o];
        __syncthreads();
      }
      if (t == 0) g_csq[c] = red[0];
    }
    grid_barrier(c, base + (++bar));  // B: new centroids visible
  }
}

// mask write: out[b,h,i,j] = (cid[b,i]==cid[b,j]) ? 0 : -10000. 16 rows/block.
__global__ void __launch_bounds__(256) k_mask(float* __restrict__ out, int H) {
  const int blk = blockIdx.x;
  const int tiles = LSEQ / 16;  // 256
  const int b = blk / (H * tiles);
  const int h = (blk / tiles) % H;
  const int tile = blk % tiles;
  const int t = threadIdx.x;
  __shared__ int cid[LSEQ];  // 16 KB
  for (int j = t; j < LSEQ; j += 256) cid[j] = g_idx[b * LSEQ + j];
  __syncthreads();
  const size_t base = ((size_t)(b * H + h) * LSEQ + (size_t)tile * 16) * LSEQ;
  for (int r = 0; r < 16; ++r) {
    const int my = cid[tile * 16 + r];
    float4* orow = (float4*)(out + base + (size_t)r * LSEQ);
#pragma unroll
    for (int s = 0; s < 4; ++s) {
      const int c4 = s * 256 + t;
      const int j = c4 * 4;
      float4 v;
      v.x = (cid[j + 0] == my) ? 0.f : -10000.f;
      v.y = (cid[j + 1] == my) ? 0.f : -10000.f;
      v.z = (cid[j + 2] == my) ? 0.f : -10000.f;
      v.w = (cid[j + 3] == my) ? 0.f : -10000.f;
      orow[c4] = v;
    }
  }
}

// ---------------- launch -----------------------------------------------------
extern "C" void kernel_launch(void* const* d_in, const int* in_sizes, int n_in,
                              void* d_out, int out_size, void* d_ws, size_t ws_size,
                              hipStream_t stream) {
  const float* qk = (const float*)d_in[0];
  const float* W = (const float*)d_in[1];
  const int H = out_size / (NB * LSEQ * LSEQ);  // 8

  const InitIdx ii = compute_init_indices();  // pure host integer math

  k_R_xsq<<<NB * (LSEQ / 8), 256, 0, stream>>>(qk, W);
  k_kmeans<<<NBLK, 1024, 0, stream>>>(ii);
  k_mask<<<NB * H * (LSEQ / 16), 256, 0, stream>>>((float*)d_out, H);
}

// Round 17
// 595.656 us; speedup vs baseline: 1.2702x; 1.0023x over previous
//
#include <hip/hip_runtime.h>
#include <stdint.h>
#include <stddef.h>
#include <vector>
#include <algorithm>
#include <utility>

// Problem constants (B=2, L=4096, D=256, H=8, K=sqrt(L)=64, 10 Lloyd iters)
#define NPTS 8192
#define DIM  256
#define KC   64
#define LSEQ 4096
#define NB   2
#define KM_ITERS 10
#define NCHUNK 64     // global summation chunks of 128 points (bit-exact structure)
#define NBLK 128      // persistent blocks: block b owns points [b*64, b*64+64)
#define NCENT 64      // blocks 0..63 also own cluster c for the cent phase
#define XPITCH 260    // padded LDS row for X tile (1040 B, 16B-aligned rows)
#define PPITCH 257    // padded LDS row for chunk-partials

// JAX threefry mode: 1 = partitionable (default since jax 0.4.36), 0 = original
#define JAX_THREEFRY_PARTITIONABLE 1

// ---------------- static device scratch (fully rewritten every call) --------
__device__ float g_R[NPTS * DIM];          // 8 MB   rotated points (read-only in kmeans)
__device__ float g_xsq[NPTS];              // 32 KB  per-point squared norm
__device__ float g_centT[DIM * KC];        // 64 KB  centroids transposed [d][k]
__device__ float g_csq[KC];                // per-centroid squared norm
__device__ int   g_idx[NPTS];              // assignments (every iter; final = cid)

// Dataflow flags (replace global barriers). Monotone across graph replays:
// each launch increments every flag exactly 11 times; each block reads its
// own flag at entry as base (all bases equal -> deterministic).
// One padded line per flag; polls are relaxed; one acquire fence per wait.
__device__ unsigned g_flag_idx[NBLK * 16];   // block c releases after assign
__device__ unsigned g_flag_cent[NCENT * 16]; // block c releases after cent/init

// ---------------- host threefry2x32 (exact JAX semantics) -------------------
static inline uint32_t rotl32(uint32_t x, int r) { return (x << r) | (x >> (32 - r)); }

static void threefry2x32(uint32_t k0, uint32_t k1, uint32_t x0, uint32_t x1,
                         uint32_t& o0, uint32_t& o1) {
  const uint32_t ks0 = k0, ks1 = k1, ks2 = k0 ^ k1 ^ 0x1BD11BDAu;
  const int r1[4] = {13, 15, 26, 6}, r2[4] = {17, 29, 16, 24};
  x0 += ks0; x1 += ks1;
  for (int i = 0; i < 4; ++i) { x0 += x1; x1 = rotl32(x1, r1[i]); x1 ^= x0; }
  x0 += ks1; x1 += ks2 + 1u;
  for (int i = 0; i < 4; ++i) { x0 += x1; x1 = rotl32(x1, r2[i]); x1 ^= x0; }
  x0 += ks2; x1 += ks0 + 2u;
  for (int i = 0; i < 4; ++i) { x0 += x1; x1 = rotl32(x1, r1[i]); x1 ^= x0; }
  x0 += ks0; x1 += ks1 + 3u;
  for (int i = 0; i < 4; ++i) { x0 += x1; x1 = rotl32(x1, r2[i]); x1 ^= x0; }
  x0 += ks1; x1 += ks2 + 4u;
  for (int i = 0; i < 4; ++i) { x0 += x1; x1 = rotl32(x1, r1[i]); x1 ^= x0; }
  x0 += ks2; x1 += ks0 + 5u;
  o0 = x0; o1 = x1;
}

struct InitIdx { int v[KC]; };

// jax.random.choice(key(42), 8192, (64,), replace=False)
//  = permutation(key, arange(8192))[:64]  (2-round threefry shuffle)
static InitIdx compute_init_indices() {
  uint32_t k0 = 0u, k1 = 42u;  // jax.random.key(42) -> [0, 42]
  std::vector<int> val(NPTS);
  for (int i = 0; i < NPTS; ++i) val[i] = i;
  std::vector<std::pair<uint32_t, int>> kv(NPTS);
  for (int round = 0; round < 2; ++round) {
    uint32_t nk0, nk1, sk0, sk1;
#if JAX_THREEFRY_PARTITIONABLE
    threefry2x32(k0, k1, 0u, 0u, nk0, nk1);
    threefry2x32(k0, k1, 0u, 1u, sk0, sk1);
    k0 = nk0; k1 = nk1;
    for (int i = 0; i < NPTS; ++i) {
      uint32_t o0, o1;
      threefry2x32(sk0, sk1, 0u, (uint32_t)i, o0, o1);
      kv[i] = std::make_pair(o0 ^ o1, val[i]);
    }
#else
    uint32_t a0, a1, b0, b1;
    threefry2x32(k0, k1, 0u, 2u, a0, a1);
    threefry2x32(k0, k1, 1u, 3u, b0, b1);
    nk0 = a0; nk1 = b0; sk0 = a1; sk1 = b1;
    k0 = nk0; k1 = nk1;
    for (int i = 0; i < NPTS / 2; ++i) {
      uint32_t o0, o1;
      threefry2x32(sk0, sk1, (uint32_t)i, (uint32_t)(i + NPTS / 2), o0, o1);
      kv[i] = std::make_pair(o0, 0);
      kv[i + NPTS / 2] = std::make_pair(o1, 0);
    }
    for (int i = 0; i < NPTS; ++i) kv[i].second = val[i];
#endif
    std::stable_sort(kv.begin(), kv.end(),
                     [](const std::pair<uint32_t, int>& a,
                        const std::pair<uint32_t, int>& b) { return a.first < b.first; });
    for (int i = 0; i < NPTS; ++i) val[i] = kv[i].second;
  }
  InitIdx ii;
  for (int k = 0; k < KC; ++k) ii.v[k] = val[k];
  return ii;
}

// ---------------- kernels ---------------------------------------------------

// Fused R-GEMM + xsq (unchanged).
__global__ void __launch_bounds__(256) k_R_xsq(const float* __restrict__ qk,
                                               const float* __restrict__ W) {
  __shared__ float q[8][DIM];
  const int blk = blockIdx.x;               // 0..1023
  const int b = blk / (LSEQ / 8);
  const int r0 = (blk % (LSEQ / 8)) * 8;
  const int t = threadIdx.x;
  for (int r = 0; r < 8; ++r)
    q[r][t] = qk[((size_t)b * LSEQ + r0 + r) * DIM + t];
  __syncthreads();
  float acc[8] = {0.f, 0.f, 0.f, 0.f, 0.f, 0.f, 0.f, 0.f};
  const float* Wb = W + (size_t)b * DIM * DIM;
  for (int d = 0; d < DIM; ++d) {
    const float w = Wb[d * DIM + t];
#pragma unroll
    for (int r = 0; r < 8; ++r) acc[r] = fmaf(q[r][d], w, acc[r]);
  }
  for (int r = 0; r < 8; ++r)
    g_R[((size_t)b * LSEQ + r0 + r) * DIM + t] = acc[r];
  __syncthreads();
  for (int r = 0; r < 8; ++r) q[r][t] = acc[r];
  __syncthreads();
  const int w = t >> 6, lane = t & 63;
#pragma unroll
  for (int rr = 0; rr < 2; ++rr) {
    const int r = w * 2 + rr;
    const float4 x = *(const float4*)&q[r][lane * 4];
    float s = x.x * x.x + x.y * x.y + x.z * x.z + x.w * x.w;
    for (int o = 32; o > 0; o >>= 1) s += __shfl_xor(s, o);
    if (lane == 0) g_xsq[(size_t)b * LSEQ + r0 + r] = s;
  }
}

// Persistent k-means, 128 blocks x 1024 threads, BARRIER-FREE dataflow:
//  - after assign, block c release-stores g_flag_idx[c].
//  - cent blocks (0..63) poll all 128 idx flags (t<128, one line each) +
//    one acquire fence, then scan; release-store g_flag_cent[c] after.
//  - assign polls the 64 cent flags (t<64) + one acquire fence.
// Race-freedom: assign(j+1) starts only after ALL cent flags >= j+1 (cent
// scans of idx(j) complete); cent(j) starts only after ALL idx flags >= j
// (centT reads of round j complete). All fp chains verbatim round-16
// -> bit-identical trajectory.
__global__ void __launch_bounds__(1024) k_kmeans(InitIdx ii) {
  __shared__ __align__(16) float CsBuf[NCHUNK * PPITCH];  // Cs[d*64+k] in assign; partials in cent
  __shared__ __align__(16) float Xs[64 * XPITCH];         // 64-row X tile (loaded once)
  __shared__ float red[256];
  __shared__ int cnt_s[NCHUNK];
  __shared__ unsigned base_s;
  const int t = threadIdx.x;          // 0..1023
  const int c = blockIdx.x;           // 0..127; owns points [c*64, c*64+64)
  const int p0 = c * 64;
  const int ptg = t >> 4;             // for t<512: 2-point group 0..31
  const int ctg = t & 15;             // 4-cluster group 0..15
  const int ct = ctg * 4;

  if (t == 0)
    base_s = __hip_atomic_load(&g_flag_idx[c * 16], __ATOMIC_RELAXED,
                               __HIP_MEMORY_SCOPE_AGENT);

  // ---- one-time: stage this block's 64 X rows + per-thread xsq ----
  for (int idx = t; idx < 64 * (DIM / 4); idx += 1024) {
    const int r = idx >> 6;
    const int dq = idx & 63;
    *(float4*)&Xs[r * XPITCH + dq * 4] =
        *(const float4*)(g_R + (size_t)(p0 + r) * DIM + dq * 4);
  }
  float xs_reg[2] = {0.f, 0.f};
  if (t < 512) {
    xs_reg[0] = g_xsq[p0 + ptg * 2 + 0];
    xs_reg[1] = g_xsq[p0 + ptg * 2 + 1];
  }
  __syncthreads();
  const unsigned base = base_s;

  // ---- init centroid k=c for c<64 (exact chain, threads 0..255) ----
  float myc = 0.f;
  if (c < NCENT) {
    if (t < 256) {
      const float cv = g_R[(size_t)ii.v[c] * DIM + t];
      myc = cv;
      g_centT[t * KC + c] = cv;
      red[t] = cv * cv;
    }
    __syncthreads();
    for (int o = 128; o > 0; o >>= 1) {
      if (t < o) red[t] += red[t + o];
      __syncthreads();
    }
    if (t == 0) {
      g_csq[c] = red[0];
    }
    __syncthreads();  // vmcnt drained: centT/csq in L2
    if (t == 0)
      __hip_atomic_store(&g_flag_cent[c * 16], base + 1u, __ATOMIC_RELEASE,
                         __HIP_MEMORY_SCOPE_AGENT);
  }

  for (int it = 0; it <= KM_ITERS; ++it) {
    const unsigned tgt = base + (unsigned)(it + 1);

    // ---- wait for all 64 centroid columns of this round ----
    if (t < NCENT) {
      while (__hip_atomic_load(&g_flag_cent[t * 16], __ATOMIC_RELAXED,
                               __HIP_MEMORY_SCOPE_AGENT) < tgt) {
        __builtin_amdgcn_s_sleep(1);
      }
    }
    __syncthreads();
    if (t == 0) __builtin_amdgcn_fence(__ATOMIC_ACQUIRE, "agent");
    __syncthreads();

    // ---- load Cs from centT (coalesced cached loads; fresh after inv) ----
    {
      float4* Cs4 = (float4*)CsBuf;
      const float4* T4 = (const float4*)g_centT;
      for (int i = t; i < (DIM * KC) / 4; i += 1024) Cs4[i] = T4[i];
    }
    __syncthreads();

    // ---- assign 64 points; threads t<512, P=2 x C=4 tile (verbatim chains) --
    if (t < 512) {
      const float cs0 = g_csq[ct + 0];
      const float cs1 = g_csq[ct + 1];
      const float cs2 = g_csq[ct + 2];
      const float cs3 = g_csq[ct + 3];

      float acc[2][4];
#pragma unroll
      for (int r = 0; r < 2; ++r)
#pragma unroll
        for (int j = 0; j < 4; ++j) acc[r][j] = 0.f;

#pragma unroll 4
      for (int d = 0; d < DIM; d += 4) {
        const float4 cv0 = *(const float4*)&CsBuf[(d + 0) * 64 + ct];
        const float4 cv1 = *(const float4*)&CsBuf[(d + 1) * 64 + ct];
        const float4 cv2 = *(const float4*)&CsBuf[(d + 2) * 64 + ct];
        const float4 cv3 = *(const float4*)&CsBuf[(d + 3) * 64 + ct];
#pragma unroll
        for (int r = 0; r < 2; ++r) {
          const float4 x = *(const float4*)&Xs[(ptg * 2 + r) * XPITCH + d];
          acc[r][0] = fmaf(x.x, cv0.x, fmaf(x.y, cv1.x, fmaf(x.z, cv2.x, fmaf(x.w, cv3.x, acc[r][0]))));
          acc[r][1] = fmaf(x.x, cv0.y, fmaf(x.y, cv1.y, fmaf(x.z, cv2.y, fmaf(x.w, cv3.y, acc[r][1]))));
          acc[r][2] = fmaf(x.x, cv0.z, fmaf(x.y, cv1.z, fmaf(x.z, cv2.z, fmaf(x.w, cv3.z, acc[r][2]))));
          acc[r][3] = fmaf(x.x, cv0.w, fmaf(x.y, cv1.w, fmaf(x.z, cv2.w, fmaf(x.w, cv3.w, acc[r][3]))));
        }
      }

#pragma unroll
      for (int r = 0; r < 2; ++r) {
        const int pl = ptg * 2 + r;
        const float xs = xs_reg[r];
        float best = 3.4e38f;
        int bk = 0;
        {
          float v;
          v = (xs - 2.0f * acc[r][0]) + cs0; if (v < best) { best = v; bk = ct + 0; }
          v = (xs - 2.0f * acc[r][1]) + cs1; if (v < best) { best = v; bk = ct + 1; }
          v = (xs - 2.0f * acc[r][2]) + cs2; if (v < best) { best = v; bk = ct + 2; }
          v = (xs - 2.0f * acc[r][3]) + cs3; if (v < best) { best = v; bk = ct + 3; }
        }
        // same 16-lane butterfly (ctg lanes within the wave), same inputs
#pragma unroll
        for (int o = 1; o < 16; o <<= 1) {
          const float ov = __shfl_xor(best, o);
          const int obk = __shfl_xor(bk, o);
          if (ov < best || (ov == best && obk < bk)) { best = ov; bk = obk; }
        }
        if (ctg == 0) g_idx[p0 + pl] = bk;   // publish every iteration
      }
    }
    __syncthreads();  // vmcnt drained: g_idx (and CsBuf reads done)
    if (t == 0)
      __hip_atomic_store(&g_flag_idx[c * 16], tgt, __ATOMIC_RELEASE,
                         __HIP_MEMORY_SCOPE_AGENT);
    if (it == KM_ITERS) break;

    // ---- cent phase: blocks 0..63 compute centroid c (verbatim chains) ----
    if (c < NCENT) {
      // wait for all 128 blocks' assignments of this round
      if (t < NBLK) {
        while (__hip_atomic_load(&g_flag_idx[t * 16], __ATOMIC_RELAXED,
                                 __HIP_MEMORY_SCOPE_AGENT) < tgt) {
          __builtin_amdgcn_s_sleep(1);
        }
      }
      __syncthreads();
      if (t == 0) __builtin_amdgcn_fence(__ATOMIC_ACQUIRE, "agent");
      __syncthreads();

      // thread (ch, dq): chunk ch's partial for cluster c, dims dq*16..+15,
      // ascending p within chunk — idx read straight from global (L2-hot).
      const int ch = t >> 4;
      const int dq = t & 15;
      float4 s[4];
#pragma unroll
      for (int q = 0; q < 4; ++q) s[q] = make_float4(0.f, 0.f, 0.f, 0.f);
      int cnt = 0;
      const int pb = ch * 128;
      for (int j4 = 0; j4 < 32; ++j4) {
        const int4 iv = *(const int4*)(g_idx + pb + j4 * 4);
        // ascending j within the quad — identical order/conditions
        if (iv.x == c) {
          const float4* row = (const float4*)(g_R + (size_t)(pb + j4 * 4 + 0) * DIM) + dq * 4;
#pragma unroll
          for (int q = 0; q < 4; ++q) { const float4 x = row[q]; s[q].x += x.x; s[q].y += x.y; s[q].z += x.z; s[q].w += x.w; }
          ++cnt;
        }
        if (iv.y == c) {
          const float4* row = (const float4*)(g_R + (size_t)(pb + j4 * 4 + 1) * DIM) + dq * 4;
#pragma unroll
          for (int q = 0; q < 4; ++q) { const float4 x = row[q]; s[q].x += x.x; s[q].y += x.y; s[q].z += x.z; s[q].w += x.w; }
          ++cnt;
        }
        if (iv.z == c) {
          const float4* row = (const float4*)(g_R + (size_t)(pb + j4 * 4 + 2) * DIM) + dq * 4;
#pragma unroll
          for (int q = 0; q < 4; ++q) { const float4 x = row[q]; s[q].x += x.x; s[q].y += x.y; s[q].z += x.z; s[q].w += x.w; }
          ++cnt;
        }
        if (iv.w == c) {
          const float4* row = (const float4*)(g_R + (size_t)(pb + j4 * 4 + 3) * DIM) + dq * 4;
#pragma unroll
          for (int q = 0; q < 4; ++q) { const float4 x = row[q]; s[q].x += x.x; s[q].y += x.y; s[q].z += x.z; s[q].w += x.w; }
          ++cnt;
        }
      }
      // stage partials in LDS (CsBuf free: assign's reads ended pre-flag)
      float* part = CsBuf;  // layout part[ch*PPITCH + d]
#pragma unroll
      for (int q = 0; q < 4; ++q)
        *(float4*)&part[ch * PPITCH + dq * 16 + q * 4] = s[q];
      if (dq == 0) cnt_s[ch] = cnt;
      __syncthreads();

      // combine in exact ascending chunk order (old upB chain), divide, csq
      if (t < 256) {
        float ssum = 0.f;
#pragma unroll 4
        for (int c2 = 0; c2 < NCHUNK; ++c2) ssum += part[c2 * PPITCH + t];
        int ctot = 0;
#pragma unroll 4
        for (int c2 = 0; c2 < NCHUNK; ++c2) ctot += cnt_s[c2];
        const float nc = (ctot > 0) ? (ssum / (float)ctot) : myc;
        myc = nc;
        g_centT[t * KC + c] = nc;
        red[t] = nc * nc;
      }
      __syncthreads();
      for (int o = 128; o > 0; o >>= 1) {
        if (t < o) red[t] += red[t + o];
        __syncthreads();
      }
      if (t == 0) g_csq[c] = red[0];
      __syncthreads();  // vmcnt drained: centT/csq in L2
      if (t == 0)
        __hip_atomic_store(&g_flag_cent[c * 16], tgt + 1u, __ATOMIC_RELEASE,
                           __HIP_MEMORY_SCOPE_AGENT);
    }
  }
}

// mask write: out[b,h,i,j] = (cid[b,i]==cid[b,j]) ? 0 : -10000. 16 rows/block.
__global__ void __launch_bounds__(256) k_mask(float* __restrict__ out, int H) {
  const int blk = blockIdx.x;
  const int tiles = LSEQ / 16;  // 256
  const int b = blk / (H * tiles);
  const int h = (blk / tiles) % H;
  const int tile = blk % tiles;
  const int t = threadIdx.x;
  __shared__ int cid[LSEQ];  // 16 KB
  for (int j = t; j < LSEQ; j += 256) cid[j] = g_idx[b * LSEQ + j];
  __syncthreads();
  const size_t base = ((size_t)(b * H + h) * LSEQ + (size_t)tile * 16) * LSEQ;
  for (int r = 0; r < 16; ++r) {
    const int my = cid[tile * 16 + r];
    float4* orow = (float4*)(out + base + (size_t)r * LSEQ);
#pragma unroll
    for (int s = 0; s < 4; ++s) {
      const int c4 = s * 256 + t;
      const int j = c4 * 4;
      float4 v;
      v.x = (cid[j + 0] == my) ? 0.f : -10000.f;
      v.y = (cid[j + 1] == my) ? 0.f : -10000.f;
      v.z = (cid[j + 2] == my) ? 0.f : -10000.f;
      v.w = (cid[j + 3] == my) ? 0.f : -10000.f;
      orow[c4] = v;
    }
  }
}

// ---------------- launch -----------------------------------------------------
extern "C" void kernel_launch(void* const* d_in, const int* in_sizes, int n_in,
                              void* d_out, int out_size, void* d_ws, size_t ws_size,
                              hipStream_t stream) {
  const float* qk = (const float*)d_in[0];
  const float* W = (const float*)d_in[1];
  const int H = out_size / (NB * LSEQ * LSEQ);  // 8

  const InitIdx ii = compute_init_indices();  // pure host integer math

  k_R_xsq<<<NB * (LSEQ / 8), 256, 0, stream>>>(qk, W);
  k_kmeans<<<NBLK, 1024, 0, stream>>>(ii);
  k_mask<<<NB * H * (LSEQ / 16), 256, 0, stream>>>((float*)d_out, H);
}

// Round 20
// 590.771 us; speedup vs baseline: 1.2807x; 1.0083x over previous
//
#include <hip/hip_runtime.h>
#include <stdint.h>
#include <stddef.h>
#include <vector>
#include <algorithm>
#include <utility>

// Problem constants (B=2, L=4096, D=256, H=8, K=sqrt(L)=64, 10 Lloyd iters)
#define NPTS 8192
#define DIM  256
#define KC   64
#define LSEQ 4096
#define NB   2
#define KM_ITERS 10
#define NCHUNK 64     // global summation chunks of 128 points (bit-exact structure)
#define NBLK 128      // persistent blocks: block b owns points [b*64, b*64+64)
#define NCENT 64      // blocks 0..63 also own cluster c for the cent phase
#define XPITCH 260    // padded LDS row for X tile (1040 B, 16B-aligned rows)
#define PPITCH 257    // padded LDS row for chunk-partials

// JAX threefry mode: 1 = partitionable (default since jax 0.4.36), 0 = original
#define JAX_THREEFRY_PARTITIONABLE 1

// native vector type for nontemporal stores (HIP float4 is a class type,
// which __builtin_nontemporal_store rejects)
typedef float nt_float4 __attribute__((ext_vector_type(4)));

// ---------------- static device scratch (fully rewritten every call) --------
__device__ float g_R[NPTS * DIM];          // 8 MB   rotated points (read-only in kmeans)
__device__ float g_xsq[NPTS];              // 32 KB  per-point squared norm
__device__ float g_centT[DIM * KC];        // 64 KB  centroids transposed [d][k]
__device__ float g_csq[KC];                // per-centroid squared norm
__device__ int   g_idx[NPTS];              // assignments (every iter; final = cid)

// Dataflow flags (replace global barriers). Monotone across graph replays:
// each launch increments every flag exactly 11 times; each block reads its
// own flag at entry as base (all bases equal -> deterministic).
__device__ unsigned g_flag_idx[NBLK * 16];   // block c releases after assign
__device__ unsigned g_flag_cent[NCENT * 16]; // block c releases after cent/init

// ---------------- host threefry2x32 (exact JAX semantics) -------------------
static inline uint32_t rotl32(uint32_t x, int r) { return (x << r) | (x >> (32 - r)); }

static void threefry2x32(uint32_t k0, uint32_t k1, uint32_t x0, uint32_t x1,
                         uint32_t& o0, uint32_t& o1) {
  const uint32_t ks0 = k0, ks1 = k1, ks2 = k0 ^ k1 ^ 0x1BD11BDAu;
  const int r1[4] = {13, 15, 26, 6}, r2[4] = {17, 29, 16, 24};
  x0 += ks0; x1 += ks1;
  for (int i = 0; i < 4; ++i) { x0 += x1; x1 = rotl32(x1, r1[i]); x1 ^= x0; }
  x0 += ks1; x1 += ks2 + 1u;
  for (int i = 0; i < 4; ++i) { x0 += x1; x1 = rotl32(x1, r2[i]); x1 ^= x0; }
  x0 += ks2; x1 += ks0 + 2u;
  for (int i = 0; i < 4; ++i) { x0 += x1; x1 = rotl32(x1, r1[i]); x1 ^= x0; }
  x0 += ks0; x1 += ks1 + 3u;
  for (int i = 0; i < 4; ++i) { x0 += x1; x1 = rotl32(x1, r2[i]); x1 ^= x0; }
  x0 += ks1; x1 += ks2 + 4u;
  for (int i = 0; i < 4; ++i) { x0 += x1; x1 = rotl32(x1, r1[i]); x1 ^= x0; }
  x0 += ks2; x1 += ks0 + 5u;
  o0 = x0; o1 = x1;
}

struct InitIdx { int v[KC]; };

// jax.random.choice(key(42), 8192, (64,), replace=False)
//  = permutation(key, arange(8192))[:64]  (2-round threefry shuffle)
static InitIdx compute_init_indices() {
  uint32_t k0 = 0u, k1 = 42u;  // jax.random.key(42) -> [0, 42]
  std::vector<int> val(NPTS);
  for (int i = 0; i < NPTS; ++i) val[i] = i;
  std::vector<std::pair<uint32_t, int>> kv(NPTS);
  for (int round = 0; round < 2; ++round) {
    uint32_t nk0, nk1, sk0, sk1;
#if JAX_THREEFRY_PARTITIONABLE
    threefry2x32(k0, k1, 0u, 0u, nk0, nk1);
    threefry2x32(k0, k1, 0u, 1u, sk0, sk1);
    k0 = nk0; k1 = nk1;
    for (int i = 0; i < NPTS; ++i) {
      uint32_t o0, o1;
      threefry2x32(sk0, sk1, 0u, (uint32_t)i, o0, o1);
      kv[i] = std::make_pair(o0 ^ o1, val[i]);
    }
#else
    uint32_t a0, a1, b0, b1;
    threefry2x32(k0, k1, 0u, 2u, a0, a1);
    threefry2x32(k0, k1, 1u, 3u, b0, b1);
    nk0 = a0; nk1 = b0; sk0 = a1; sk1 = b1;
    k0 = nk0; k1 = nk1;
    for (int i = 0; i < NPTS / 2; ++i) {
      uint32_t o0, o1;
      threefry2x32(sk0, sk1, (uint32_t)i, (uint32_t)(i + NPTS / 2), o0, o1);
      kv[i] = std::make_pair(o0, 0);
      kv[i + NPTS / 2] = std::make_pair(o1, 0);
    }
    for (int i = 0; i < NPTS; ++i) kv[i].second = val[i];
#endif
    std::stable_sort(kv.begin(), kv.end(),
                     [](const std::pair<uint32_t, int>& a,
                        const std::pair<uint32_t, int>& b) { return a.first < b.first; });
    for (int i = 0; i < NPTS; ++i) val[i] = kv[i].second;
  }
  InitIdx ii;
  for (int k = 0; k < KC; ++k) ii.v[k] = val[k];
  return ii;
}

// ---------------- kernels ---------------------------------------------------

// Fused R-GEMM + xsq (unchanged).
__global__ void __launch_bounds__(256) k_R_xsq(const float* __restrict__ qk,
                                               const float* __restrict__ W) {
  __shared__ float q[8][DIM];
  const int blk = blockIdx.x;               // 0..1023
  const int b = blk / (LSEQ / 8);
  const int r0 = (blk % (LSEQ / 8)) * 8;
  const int t = threadIdx.x;
  for (int r = 0; r < 8; ++r)
    q[r][t] = qk[((size_t)b * LSEQ + r0 + r) * DIM + t];
  __syncthreads();
  float acc[8] = {0.f, 0.f, 0.f, 0.f, 0.f, 0.f, 0.f, 0.f};
  const float* Wb = W + (size_t)b * DIM * DIM;
  for (int d = 0; d < DIM; ++d) {
    const float w = Wb[d * DIM + t];
#pragma unroll
    for (int r = 0; r < 8; ++r) acc[r] = fmaf(q[r][d], w, acc[r]);
  }
  for (int r = 0; r < 8; ++r)
    g_R[((size_t)b * LSEQ + r0 + r) * DIM + t] = acc[r];
  __syncthreads();
  for (int r = 0; r < 8; ++r) q[r][t] = acc[r];
  __syncthreads();
  const int w = t >> 6, lane = t & 63;
#pragma unroll
  for (int rr = 0; rr < 2; ++rr) {
    const int r = w * 2 + rr;
    const float4 x = *(const float4*)&q[r][lane * 4];
    float s = x.x * x.x + x.y * x.y + x.z * x.z + x.w * x.w;
    for (int o = 32; o > 0; o >>= 1) s += __shfl_xor(s, o);
    if (lane == 0) g_xsq[(size_t)b * LSEQ + r0 + r] = s;
  }
}

// Persistent k-means (byte-identical structure to round 17, which passed).
__global__ void __launch_bounds__(1024) k_kmeans(InitIdx ii) {
  __shared__ __align__(16) float CsBuf[NCHUNK * PPITCH];  // Cs[d*64+k] in assign; partials in cent
  __shared__ __align__(16) float Xs[64 * XPITCH];         // 64-row X tile (loaded once)
  __shared__ float red[256];
  __shared__ int cnt_s[NCHUNK];
  __shared__ unsigned base_s;
  const int t = threadIdx.x;          // 0..1023
  const int c = blockIdx.x;           // 0..127; owns points [c*64, c*64+64)
  const int p0 = c * 64;
  const int ptg = t >> 4;             // for t<512: 2-point group 0..31
  const int ctg = t & 15;             // 4-cluster group 0..15
  const int ct = ctg * 4;

  if (t == 0)
    base_s = __hip_atomic_load(&g_flag_idx[c * 16], __ATOMIC_RELAXED,
                               __HIP_MEMORY_SCOPE_AGENT);

  // ---- one-time: stage this block's 64 X rows + per-thread xsq ----
  for (int idx = t; idx < 64 * (DIM / 4); idx += 1024) {
    const int r = idx >> 6;
    const int dq = idx & 63;
    *(float4*)&Xs[r * XPITCH + dq * 4] =
        *(const float4*)(g_R + (size_t)(p0 + r) * DIM + dq * 4);
  }
  float xs_reg[2] = {0.f, 0.f};
  if (t < 512) {
    xs_reg[0] = g_xsq[p0 + ptg * 2 + 0];
    xs_reg[1] = g_xsq[p0 + ptg * 2 + 1];
  }
  __syncthreads();
  const unsigned base = base_s;

  // ---- init centroid k=c for c<64 (exact chain, threads 0..255) ----
  float myc = 0.f;
  if (c < NCENT) {
    if (t < 256) {
      const float cv = g_R[(size_t)ii.v[c] * DIM + t];
      myc = cv;
      g_centT[t * KC + c] = cv;
      red[t] = cv * cv;
    }
    __syncthreads();
    for (int o = 128; o > 0; o >>= 1) {
      if (t < o) red[t] += red[t + o];
      __syncthreads();
    }
    if (t == 0) {
      g_csq[c] = red[0];
    }
    __syncthreads();  // vmcnt drained: centT/csq in L2
    if (t == 0)
      __hip_atomic_store(&g_flag_cent[c * 16], base + 1u, __ATOMIC_RELEASE,
                         __HIP_MEMORY_SCOPE_AGENT);
  }

  for (int it = 0; it <= KM_ITERS; ++it) {
    const unsigned tgt = base + (unsigned)(it + 1);

    // ---- wait for all 64 centroid columns of this round ----
    if (t < NCENT) {
      while (__hip_atomic_load(&g_flag_cent[t * 16], __ATOMIC_RELAXED,
                               __HIP_MEMORY_SCOPE_AGENT) < tgt) {
        __builtin_amdgcn_s_sleep(1);
      }
    }
    __syncthreads();
    if (t == 0) __builtin_amdgcn_fence(__ATOMIC_ACQUIRE, "agent");
    __syncthreads();

    // ---- load Cs from centT (coalesced cached loads; fresh after inv) ----
    {
      float4* Cs4 = (float4*)CsBuf;
      const float4* T4 = (const float4*)g_centT;
      for (int i = t; i < (DIM * KC) / 4; i += 1024) Cs4[i] = T4[i];
    }
    __syncthreads();

    // ---- assign 64 points; threads t<512, P=2 x C=4 tile (verbatim chains) --
    if (t < 512) {
      const float cs0 = g_csq[ct + 0];
      const float cs1 = g_csq[ct + 1];
      const float cs2 = g_csq[ct + 2];
      const float cs3 = g_csq[ct + 3];

      float acc[2][4];
#pragma unroll
      for (int r = 0; r < 2; ++r)
#pragma unroll
        for (int j = 0; j < 4; ++j) acc[r][j] = 0.f;

#pragma unroll 4
      for (int d = 0; d < DIM; d += 4) {
        const float4 cv0 = *(const float4*)&CsBuf[(d + 0) * 64 + ct];
        const float4 cv1 = *(const float4*)&CsBuf[(d + 1) * 64 + ct];
        const float4 cv2 = *(const float4*)&CsBuf[(d + 2) * 64 + ct];
        const float4 cv3 = *(const float4*)&CsBuf[(d + 3) * 64 + ct];
#pragma unroll
        for (int r = 0; r < 2; ++r) {
          const float4 x = *(const float4*)&Xs[(ptg * 2 + r) * XPITCH + d];
          acc[r][0] = fmaf(x.x, cv0.x, fmaf(x.y, cv1.x, fmaf(x.z, cv2.x, fmaf(x.w, cv3.x, acc[r][0]))));
          acc[r][1] = fmaf(x.x, cv0.y, fmaf(x.y, cv1.y, fmaf(x.z, cv2.y, fmaf(x.w, cv3.y, acc[r][1]))));
          acc[r][2] = fmaf(x.x, cv0.z, fmaf(x.y, cv1.z, fmaf(x.z, cv2.z, fmaf(x.w, cv3.z, acc[r][2]))));
          acc[r][3] = fmaf(x.x, cv0.w, fmaf(x.y, cv1.w, fmaf(x.z, cv2.w, fmaf(x.w, cv3.w, acc[r][3]))));
        }
      }

#pragma unroll
      for (int r = 0; r < 2; ++r) {
        const int pl = ptg * 2 + r;
        const float xs = xs_reg[r];
        float best = 3.4e38f;
        int bk = 0;
        {
          float v;
          v = (xs - 2.0f * acc[r][0]) + cs0; if (v < best) { best = v; bk = ct + 0; }
          v = (xs - 2.0f * acc[r][1]) + cs1; if (v < best) { best = v; bk = ct + 1; }
          v = (xs - 2.0f * acc[r][2]) + cs2; if (v < best) { best = v; bk = ct + 2; }
          v = (xs - 2.0f * acc[r][3]) + cs3; if (v < best) { best = v; bk = ct + 3; }
        }
        // same 16-lane butterfly (ctg lanes within the wave), same inputs
#pragma unroll
        for (int o = 1; o < 16; o <<= 1) {
          const float ov = __shfl_xor(best, o);
          const int obk = __shfl_xor(bk, o);
          if (ov < best || (ov == best && obk < bk)) { best = ov; bk = obk; }
        }
        if (ctg == 0) g_idx[p0 + pl] = bk;   // publish every iteration
      }
    }
    __syncthreads();  // vmcnt drained: g_idx (and CsBuf reads done)
    if (t == 0)
      __hip_atomic_store(&g_flag_idx[c * 16], tgt, __ATOMIC_RELEASE,
                         __HIP_MEMORY_SCOPE_AGENT);
    if (it == KM_ITERS) break;

    // ---- cent phase: blocks 0..63 compute centroid c (verbatim chains) ----
    if (c < NCENT) {
      // wait for all 128 blocks' assignments of this round
      if (t < NBLK) {
        while (__hip_atomic_load(&g_flag_idx[t * 16], __ATOMIC_RELAXED,
                                 __HIP_MEMORY_SCOPE_AGENT) < tgt) {
          __builtin_amdgcn_s_sleep(1);
        }
      }
      __syncthreads();
      if (t == 0) __builtin_amdgcn_fence(__ATOMIC_ACQUIRE, "agent");
      __syncthreads();

      // thread (ch, dq): chunk ch's partial for cluster c, dims dq*16..+15,
      // ascending p within chunk — idx read straight from global (L2-hot).
      const int ch = t >> 4;
      const int dq = t & 15;
      float4 s[4];
#pragma unroll
      for (int q = 0; q < 4; ++q) s[q] = make_float4(0.f, 0.f, 0.f, 0.f);
      int cnt = 0;
      const int pb = ch * 128;
      for (int j4 = 0; j4 < 32; ++j4) {
        const int4 iv = *(const int4*)(g_idx + pb + j4 * 4);
        // ascending j within the quad — identical order/conditions
        if (iv.x == c) {
          const float4* row = (const float4*)(g_R + (size_t)(pb + j4 * 4 + 0) * DIM) + dq * 4;
#pragma unroll
          for (int q = 0; q < 4; ++q) { const float4 x = row[q]; s[q].x += x.x; s[q].y += x.y; s[q].z += x.z; s[q].w += x.w; }
          ++cnt;
        }
        if (iv.y == c) {
          const float4* row = (const float4*)(g_R + (size_t)(pb + j4 * 4 + 1) * DIM) + dq * 4;
#pragma unroll
          for (int q = 0; q < 4; ++q) { const float4 x = row[q]; s[q].x += x.x; s[q].y += x.y; s[q].z += x.z; s[q].w += x.w; }
          ++cnt;
        }
        if (iv.z == c) {
          const float4* row = (const float4*)(g_R + (size_t)(pb + j4 * 4 + 2) * DIM) + dq * 4;
#pragma unroll
          for (int q = 0; q < 4; ++q) { const float4 x = row[q]; s[q].x += x.x; s[q].y += x.y; s[q].z += x.z; s[q].w += x.w; }
          ++cnt;
        }
        if (iv.w == c) {
          const float4* row = (const float4*)(g_R + (size_t)(pb + j4 * 4 + 3) * DIM) + dq * 4;
#pragma unroll
          for (int q = 0; q < 4; ++q) { const float4 x = row[q]; s[q].x += x.x; s[q].y += x.y; s[q].z += x.z; s[q].w += x.w; }
          ++cnt;
        }
      }
      // stage partials in LDS (CsBuf free: assign's reads ended pre-flag)
      float* part = CsBuf;  // layout part[ch*PPITCH + d]
#pragma unroll
      for (int q = 0; q < 4; ++q)
        *(float4*)&part[ch * PPITCH + dq * 16 + q * 4] = s[q];
      if (dq == 0) cnt_s[ch] = cnt;
      __syncthreads();

      // combine in exact ascending chunk order (old upB chain), divide, csq
      if (t < 256) {
        float ssum = 0.f;
#pragma unroll 4
        for (int c2 = 0; c2 < NCHUNK; ++c2) ssum += part[c2 * PPITCH + t];
        int ctot = 0;
#pragma unroll 4
        for (int c2 = 0; c2 < NCHUNK; ++c2) ctot += cnt_s[c2];
        const float nc = (ctot > 0) ? (ssum / (float)ctot) : myc;
        myc = nc;
        g_centT[t * KC + c] = nc;
        red[t] = nc * nc;
      }
      __syncthreads();
      for (int o = 128; o > 0; o >>= 1) {
        if (t < o) red[t] += red[t + o];
        __syncthreads();
      }
      if (t == 0) g_csq[c] = red[0];
      __syncthreads();  // vmcnt drained: centT/csq in L2
      if (t == 0)
        __hip_atomic_store(&g_flag_cent[c * 16], tgt + 1u, __ATOMIC_RELEASE,
                           __HIP_MEMORY_SCOPE_AGENT);
    }
  }
}

// mask write: out[b,h,i,j] = (cid[b,i]==cid[b,j]) ? 0 : -10000.
// 1024 blocks x 1024 threads, 64 rows/block. Per thread: its 4-column quad
// (iv) is ROW-INVARIANT -> hoisted to registers; per row = 1 LDS broadcast
// (my) + 4 compares + 1 nontemporal 16B store (coalesced: thread t covers
// float4 #t of the row).
__global__ void __launch_bounds__(1024) k_mask(float* __restrict__ out, int H) {
  const int blk = blockIdx.x;
  const int tiles = LSEQ / 64;  // 64 row-tiles per (b,h)
  const int b = blk / (H * tiles);
  const int h = (blk / tiles) % H;
  const int tile = blk % tiles;
  const int t = threadIdx.x;
  __shared__ int cid[LSEQ];  // 16 KB
  {
    int4* dst = (int4*)cid;
    const int4* src = (const int4*)(g_idx + b * LSEQ);
    dst[t] = src[t];  // 1024 int4 = 4096 ints
  }
  __syncthreads();
  const int4 iv = ((const int4*)cid)[t];  // this thread's columns 4t..4t+3
  const size_t base = ((size_t)(b * H + h) * LSEQ + (size_t)tile * 64) * LSEQ;
  nt_float4* orow = (nt_float4*)(out + base) + t;
#pragma unroll 4
  for (int r = 0; r < 64; ++r) {
    const int my = cid[tile * 64 + r];  // LDS broadcast (free)
    nt_float4 v;
    v.x = (iv.x == my) ? 0.f : -10000.f;
    v.y = (iv.y == my) ? 0.f : -10000.f;
    v.z = (iv.z == my) ? 0.f : -10000.f;
    v.w = (iv.w == my) ? 0.f : -10000.f;
    __builtin_nontemporal_store(v, orow);
    orow += LSEQ / 4;
  }
}

// ---------------- launch -----------------------------------------------------
extern "C" void kernel_launch(void* const* d_in, const int* in_sizes, int n_in,
                              void* d_out, int out_size, void* d_ws, size_t ws_size,
                              hipStream_t stream) {
  const float* qk = (const float*)d_in[0];
  const float* W = (const float*)d_in[1];
  const int H = out_size / (NB * LSEQ * LSEQ);  // 8

  const InitIdx ii = compute_init_indices();  // pure host integer math

  k_R_xsq<<<NB * (LSEQ / 8), 256, 0, stream>>>(qk, W);
  k_kmeans<<<NBLK, 1024, 0, stream>>>(ii);
  k_mask<<<NB * H * (LSEQ / 64), 1024, 0, stream>>>((float*)d_out, H);
}